// Round 14
// baseline (425.374 us; speedup 1.0000x reference)
//
#include <hip/hip_runtime.h>
#include <math.h>

// ---------------------------------------------------------------------------
// RFSQDraftModelWithProjection — f32 in / f32 out, bf16 MFMA compute.
// r14: gemm128 (m97 128x128 tile, 16 MFMA/step) for GEMM1/attn/FF1/heads2;
// gemm64 retained for FF2/heads1/Wct. m-tile on blockIdx.x (XCD L2 reuse),
// counted-vmcnt double buffering, AF32 depth-2 register prefetch, split-K.
// ---------------------------------------------------------------------------

typedef unsigned short u16;
typedef __attribute__((ext_vector_type(8))) short bf16x8;
typedef __attribute__((ext_vector_type(4))) float f32x4;
typedef __attribute__((ext_vector_type(8))) unsigned short u16x8;
typedef __attribute__((ext_vector_type(4))) unsigned short u16x4;

__device__ __forceinline__ float bf2f(u16 u){
    union { unsigned int i; float f; } x; x.i = ((unsigned int)u) << 16; return x.f;
}
__device__ __forceinline__ u16 f2bf(float f){
    union { float f; unsigned int i; } x; x.f = f;
    unsigned int r = x.i + 0x7fffu + ((x.i >> 16) & 1u);
    return (u16)(r >> 16);
}
__device__ __forceinline__ float gelu_exact(float v){
    return 0.5f * v * (1.0f + erff(v * 0.7071067811865475f));
}
#define GLOAD16(src, dst) __builtin_amdgcn_global_load_lds( \
    (const __attribute__((address_space(1))) void*)(src),   \
    (__attribute__((address_space(3))) void*)(dst), 16, 0, 0)
#define SCHED0 __builtin_amdgcn_sched_barrier(0)

// ---------------------------------------------------------------------------
// gemm128: 128x128 tile, BK=32, 4 waves (2x2 of 64x64), 16 MFMA/step.
// blockIdx.x = m-tile, blockIdx.y = n-tile. Counted-vmcnt double buffer.
// AF32: depth-2 reg prefetch (4 float4/thread/tile). PART: blockIdx.z =
// k-chunk, raw f32 partials at Cout + z*czs. Else z = batch via strides.
// ---------------------------------------------------------------------------
template<bool GELU, bool RES, bool AF32, bool OUTF32, bool PART>
__global__ __launch_bounds__(256) void gemm128(
    const void* __restrict__ A, const void* __restrict__ A2, int ksplit,
    const u16* __restrict__ Bt, const float* __restrict__ bias,
    const u16* __restrict__ res, int ldr,
    void* __restrict__ Cout, int K, int lda, int ldb, int ldc,
    long azs, long bzs, int biaszs, long czs, int kch)
{
    __shared__ __align__(16) u16 As[2][128 * 32];
    __shared__ __align__(16) u16 Bs[2][128 * 32];
    const int tid = threadIdx.x;
    const int w = tid >> 6, l = tid & 63;
    const int wr = w >> 1, wc = w & 1;
    const int m0 = blockIdx.x * 128, n0 = blockIdx.y * 128;
    const int z = blockIdx.z;
    int kbeg = 0, kend = K;
    if (PART) { kbeg = z * kch; kend = min(kbeg + kch, K); }
    const u16* A16 = (const u16*)A + (PART ? 0 : (size_t)z * azs);
    const float* Af = (const float*)A;
    const u16* BtZ = Bt + (PART ? 0 : (size_t)z * bzs);

    f32x4 acc[4][4];
#pragma unroll
    for (int i = 0; i < 4; ++i)
#pragma unroll
        for (int j = 0; j < 4; ++j) acc[i][j] = (f32x4){0.f, 0.f, 0.f, 0.f};

    auto stageB = [&](int buf, int k0) {
#pragma unroll
        for (int j = 0; j < 2; ++j) {
            const int rr = (w * 2 + j) * 16 + (l >> 2);
            const u16* gb = BtZ + (size_t)(n0 + rr) * ldb + k0 + (l & 3) * 8;
            GLOAD16(gb, &Bs[buf][(w * 2 + j) * 512]);
        }
    };
    auto stageA16 = [&](int buf, int k0) {
        const u16* base = (k0 >= ksplit) ? ((const u16*)A2 + (k0 - ksplit)) : (A16 + k0);
#pragma unroll
        for (int j = 0; j < 2; ++j) {
            const int rr = (w * 2 + j) * 16 + (l >> 2);
            const u16* ga = base + (size_t)(m0 + rr) * lda + (l & 3) * 8;
            GLOAD16(ga, &As[buf][(w * 2 + j) * 512]);
        }
    };
    // AF32: thread covers row tid>>1, cols (tid&1)*16 .. +15 (4 float4)
    auto loadA = [&](int k0, float4& p0, float4& p1, float4& p2, float4& p3) {
        const float* g = Af + (size_t)(m0 + (tid >> 1)) * lda + k0 + (tid & 1) * 16;
        p0 = *(const float4*)g;       p1 = *(const float4*)(g + 4);
        p2 = *(const float4*)(g + 8); p3 = *(const float4*)(g + 12);
    };
    auto writeA = [&](const float4& p0, const float4& p1, const float4& p2,
                      const float4& p3, int buf) {
        u16x8 v0, v1;
        v0[0] = f2bf(p0.x); v0[1] = f2bf(p0.y); v0[2] = f2bf(p0.z); v0[3] = f2bf(p0.w);
        v0[4] = f2bf(p1.x); v0[5] = f2bf(p1.y); v0[6] = f2bf(p1.z); v0[7] = f2bf(p1.w);
        v1[0] = f2bf(p2.x); v1[1] = f2bf(p2.y); v1[2] = f2bf(p2.z); v1[3] = f2bf(p2.w);
        v1[4] = f2bf(p3.x); v1[5] = f2bf(p3.y); v1[6] = f2bf(p3.z); v1[7] = f2bf(p3.w);
        u16* dst = &As[buf][(tid >> 1) * 32 + (tid & 1) * 16];
        *(u16x8*)dst = v0;
        *(u16x8*)(dst + 8) = v1;
    };
    int cur = 0;
    auto compute = [&]() {
        bf16x8 a[4], b[4];
#pragma unroll
        for (int i = 0; i < 4; ++i)
            a[i] = *(const bf16x8*)&As[cur][(wr * 64 + i * 16 + (l & 15)) * 32 + (l >> 4) * 8];
#pragma unroll
        for (int j = 0; j < 4; ++j)
            b[j] = *(const bf16x8*)&Bs[cur][(wc * 64 + j * 16 + (l & 15)) * 32 + (l >> 4) * 8];
#pragma unroll
        for (int i = 0; i < 4; ++i)
#pragma unroll
            for (int j = 0; j < 4; ++j)
                acc[i][j] = __builtin_amdgcn_mfma_f32_16x16x32_bf16(a[i], b[j], acc[i][j], 0, 0, 0);
    };

    const int nt = (kend - kbeg) >> 5;
    if (AF32) {
        float4 a0, a1, a2, a3, b0, b1, b2, b3;
        loadA(kbeg, a0, a1, a2, a3);
        stageB(0, kbeg);
        if (nt > 1) {
            loadA(kbeg + 32, b0, b1, b2, b3);
            asm volatile("s_waitcnt vmcnt(6)" ::: "memory");
        } else {
            asm volatile("s_waitcnt vmcnt(2)" ::: "memory");
        }
        writeA(a0, a1, a2, a3, 0);
        asm volatile("s_waitcnt lgkmcnt(0)" ::: "memory");
        auto stepA = [&](int t, float4& w0, float4& w1, float4& w2, float4& w3,
                         float4& l0, float4& l1, float4& l2, float4& l3) {
            const bool ldA = (t + 2) < nt;
            const bool stB = (t + 1) < nt;
            if (ldA) loadA(kbeg + ((t + 2) << 5), l0, l1, l2, l3);
            if (stB) stageB(cur ^ 1, kbeg + ((t + 1) << 5));
            if (ldA)      asm volatile("s_waitcnt vmcnt(6)" ::: "memory");
            else if (stB) asm volatile("s_waitcnt vmcnt(2)" ::: "memory");
            else          asm volatile("s_waitcnt vmcnt(0)" ::: "memory");
            SCHED0;
            __builtin_amdgcn_s_barrier();
            SCHED0;
            compute();
            if (stB) writeA(w0, w1, w2, w3, cur ^ 1);
            asm volatile("s_waitcnt lgkmcnt(0)" ::: "memory");
            SCHED0;
            __builtin_amdgcn_s_barrier();
            SCHED0;
            cur ^= 1;
        };
        int t = 0;
        while (t + 2 <= nt) {
            stepA(t,     b0, b1, b2, b3, a0, a1, a2, a3);
            stepA(t + 1, a0, a1, a2, a3, b0, b1, b2, b3);
            t += 2;
        }
        if (t < nt) stepA(t, b0, b1, b2, b3, a0, a1, a2, a3);
    } else {
        stageA16(0, kbeg);
        stageB(0, kbeg);
        for (int t = 0; t < nt; ++t) {
            const bool more = (t + 1) < nt;
            if (more) {
                const int kn = kbeg + ((t + 1) << 5);
                stageA16(cur ^ 1, kn);
                stageB(cur ^ 1, kn);
            }
            if (more) asm volatile("s_waitcnt vmcnt(4)" ::: "memory");
            else      asm volatile("s_waitcnt vmcnt(0)" ::: "memory");
            SCHED0;
            __builtin_amdgcn_s_barrier();
            SCHED0;
            compute();
            asm volatile("" ::: "memory");
            SCHED0;
            __builtin_amdgcn_s_barrier();
            SCHED0;
            cur ^= 1;
        }
    }

    // epilogue: C/D layout col = l&15, row = (l>>4)*4 + r  [m89/m91]
    float* cF = (float*)Cout + (size_t)z * czs;
    u16*   cH = (u16*)Cout + (size_t)z * czs;
    const float* biasZ = (!PART && bias) ? bias + (size_t)z * biaszs : nullptr;
#pragma unroll
    for (int i = 0; i < 4; ++i) {
#pragma unroll
        for (int j = 0; j < 4; ++j) {
            const int col = n0 + wc * 64 + j * 16 + (l & 15);
            const int rowb = m0 + wr * 64 + i * 16 + (l >> 4) * 4;
#pragma unroll
            for (int r = 0; r < 4; ++r) {
                const int row = rowb + r;
                float v = acc[i][j][r];
                if (PART) {
                    cF[(size_t)row * ldc + col] = v;
                } else {
                    if (biasZ) v += biasZ[col];
                    if (RES) v += bf2f(res[(size_t)row * ldr + col]);
                    if (GELU) v = gelu_exact(v);
                    if (OUTF32) cF[(size_t)row * ldc + col] = v;
                    else        cH[(size_t)row * ldc + col] = f2bf(v);
                }
            }
        }
    }
}

// ---------------------------------------------------------------------------
// gemm64: 64x128 tile, BK=32, 8 MFMA/step (r13 version) — for FF2/heads1/Wct.
// ---------------------------------------------------------------------------
template<bool GELU, bool RES, bool OUTF32, bool PART>
__global__ __launch_bounds__(256) void gemm64(
    const void* __restrict__ A, const void* __restrict__ A2, int ksplit,
    const u16* __restrict__ Bt, const float* __restrict__ bias,
    const u16* __restrict__ res, int ldr,
    void* __restrict__ Cout, int K, int lda, int ldb, int ldc,
    long azs, long bzs, int biaszs, long czs, int kch)
{
    __shared__ __align__(16) u16 As[2][64 * 32];
    __shared__ __align__(16) u16 Bs[2][128 * 32];
    const int tid = threadIdx.x;
    const int w = tid >> 6, l = tid & 63;
    const int wr = w >> 1, wc = w & 1;
    const int m0 = blockIdx.x * 64, n0 = blockIdx.y * 128;
    const int z = blockIdx.z;
    int kbeg = 0, kend = K;
    if (PART) { kbeg = z * kch; kend = min(kbeg + kch, K); }
    const u16* A16 = (const u16*)A + (PART ? 0 : (size_t)z * azs);
    const u16* BtZ = Bt + (PART ? 0 : (size_t)z * bzs);

    f32x4 acc[2][4];
#pragma unroll
    for (int i = 0; i < 2; ++i)
#pragma unroll
        for (int j = 0; j < 4; ++j) acc[i][j] = (f32x4){0.f, 0.f, 0.f, 0.f};

    auto stageB = [&](int buf, int k0) {
#pragma unroll
        for (int j = 0; j < 2; ++j) {
            const u16* gb = BtZ + (size_t)(n0 + (w * 2 + j) * 16 + (l >> 2)) * ldb
                          + k0 + (l & 3) * 8;
            GLOAD16(gb, &Bs[buf][(w * 2 + j) * 512]);
        }
    };
    auto stageA16 = [&](int buf, int k0) {
        const u16* base = (k0 >= ksplit) ? ((const u16*)A2 + (k0 - ksplit)) : (A16 + k0);
        const u16* ga = base + (size_t)(m0 + w * 16 + (l >> 2)) * lda + (l & 3) * 8;
        GLOAD16(ga, &As[buf][w * 512]);
    };
    int cur = 0;
    auto compute = [&]() {
        bf16x8 a[2], b[4];
#pragma unroll
        for (int i = 0; i < 2; ++i)
            a[i] = *(const bf16x8*)&As[cur][(wr * 32 + i * 16 + (l & 15)) * 32 + (l >> 4) * 8];
#pragma unroll
        for (int j = 0; j < 4; ++j)
            b[j] = *(const bf16x8*)&Bs[cur][(wc * 64 + j * 16 + (l & 15)) * 32 + (l >> 4) * 8];
#pragma unroll
        for (int i = 0; i < 2; ++i)
#pragma unroll
            for (int j = 0; j < 4; ++j)
                acc[i][j] = __builtin_amdgcn_mfma_f32_16x16x32_bf16(a[i], b[j], acc[i][j], 0, 0, 0);
    };

    const int nt = (kend - kbeg) >> 5;
    stageA16(0, kbeg);
    stageB(0, kbeg);
    for (int t = 0; t < nt; ++t) {
        const bool more = (t + 1) < nt;
        if (more) {
            const int kn = kbeg + ((t + 1) << 5);
            stageA16(cur ^ 1, kn);
            stageB(cur ^ 1, kn);
        }
        if (more) asm volatile("s_waitcnt vmcnt(3)" ::: "memory");
        else      asm volatile("s_waitcnt vmcnt(0)" ::: "memory");
        SCHED0;
        __builtin_amdgcn_s_barrier();
        SCHED0;
        compute();
        asm volatile("" ::: "memory");
        SCHED0;
        __builtin_amdgcn_s_barrier();
        SCHED0;
        cur ^= 1;
    }

    float* cF = (float*)Cout + (size_t)z * czs;
    u16*   cH = (u16*)Cout + (size_t)z * czs;
    const float* biasZ = (!PART && bias) ? bias + (size_t)z * biaszs : nullptr;
#pragma unroll
    for (int i = 0; i < 2; ++i) {
#pragma unroll
        for (int j = 0; j < 4; ++j) {
            const int col = n0 + wc * 64 + j * 16 + (l & 15);
            const int rowb = m0 + wr * 32 + i * 16 + (l >> 4) * 4;
#pragma unroll
            for (int r = 0; r < 4; ++r) {
                const int row = rowb + r;
                float v = acc[i][j][r];
                if (PART) {
                    cF[(size_t)row * ldc + col] = v;
                } else {
                    if (biasZ) v += biasZ[col];
                    if (RES) v += bf2f(res[(size_t)row * ldr + col]);
                    if (GELU) v = gelu_exact(v);
                    if (OUTF32) cF[(size_t)row * ldc + col] = v;
                    else        cH[(size_t)row * ldc + col] = f2bf(v);
                }
            }
        }
    }
}

// split-K reduce over [8192,512]: out = bf16(sum_p part[p] + bias (+res))
template<int NP>
__global__ __launch_bounds__(256) void reduceK(
    const float* __restrict__ part, long pzs, const float* __restrict__ bias,
    const u16* __restrict__ res, u16* __restrict__ out)
{
    const int idx = (blockIdx.x * 256 + threadIdx.x) * 4;
    const int col = idx & 511;
    float4 s = *(const float4*)(part + idx);
#pragma unroll
    for (int p = 1; p < NP; ++p) {
        const float4 v = *(const float4*)(part + (size_t)p * pzs + idx);
        s.x += v.x; s.y += v.y; s.z += v.z; s.w += v.w;
    }
    const float4 b = *(const float4*)(bias + col);
    s.x += b.x; s.y += b.y; s.z += b.z; s.w += b.w;
    if (res) {
        const u16x4 r = *(const u16x4*)(res + idx);
        s.x += bf2f(r[0]); s.y += bf2f(r[1]); s.z += bf2f(r[2]); s.w += bf2f(r[3]);
    }
    u16x4 o;
    o[0] = f2bf(s.x); o[1] = f2bf(s.y); o[2] = f2bf(s.z); o[3] = f2bf(s.w);
    *(u16x4*)(out + idx) = o;
}

// f32 -> bf16 bulk convert, 8 elems/thread
__global__ __launch_bounds__(256) void cvt_f32_bf16(
    const float* __restrict__ in, u16* __restrict__ out, int n8)
{
    const int i = blockIdx.x * 256 + threadIdx.x;
    if (i >= n8) return;
    const float4* p = (const float4*)in + (size_t)i * 2;
    const float4 a = p[0], b = p[1];
    u16x8 v;
    v[0] = f2bf(a.x); v[1] = f2bf(a.y); v[2] = f2bf(a.z); v[3] = f2bf(a.w);
    v[4] = f2bf(b.x); v[5] = f2bf(b.y); v[6] = f2bf(b.z); v[7] = f2bf(b.w);
    *(u16x8*)(out + (size_t)i * 8) = v;
}

// LayerNorm over 512 cols (bf16 in/out, f32 g/b), one wave per row
__global__ __launch_bounds__(256) void ln512_kernel(
    const u16* __restrict__ in, const float* __restrict__ g,
    const float* __restrict__ b, u16* __restrict__ out)
{
    const int wid = threadIdx.x >> 6, l = threadIdx.x & 63;
    const size_t row = (size_t)blockIdx.x * 4 + wid;
    u16x8 v = *(const u16x8*)(in + row * 512 + l * 8);
    float f[8], s = 0.f, q = 0.f;
#pragma unroll
    for (int j = 0; j < 8; ++j) { f[j] = bf2f(v[j]); s += f[j]; q += f[j] * f[j]; }
#pragma unroll
    for (int o = 32; o > 0; o >>= 1) { s += __shfl_xor(s, o); q += __shfl_xor(q, o); }
    const float mean = s * (1.f / 512.f);
    const float var = q * (1.f / 512.f) - mean * mean;
    const float rstd = rsqrtf(var + 1e-5f);
    u16x8 ov;
#pragma unroll
    for (int j = 0; j < 8; ++j) {
        const int c = l * 8 + j;
        ov[j] = f2bf((f[j] - mean) * rstd * g[c] + b[c]);
    }
    *(u16x8*)(out + row * 512 + l * 8) = ov;
}

// per-head LN over 256 (rows are [8192,768], heads of 256), wave per (row,head)
__global__ __launch_bounds__(256) void lnh_kernel(
    const u16* __restrict__ in, const float* __restrict__ g,
    const float* __restrict__ b, u16* __restrict__ out)
{
    const int wid = threadIdx.x >> 6, l = threadIdx.x & 63;
    const int unit = blockIdx.x * 4 + wid;        // unit = h*8192 + row
    const int h = unit >> 13, row = unit & 8191;
    const size_t base = (size_t)row * 768 + h * 256 + l * 4;
    u16x4 v = *(const u16x4*)(in + base);
    float f[4], s = 0.f, q = 0.f;
#pragma unroll
    for (int j = 0; j < 4; ++j) { f[j] = bf2f(v[j]); s += f[j]; q += f[j] * f[j]; }
#pragma unroll
    for (int o = 32; o > 0; o >>= 1) { s += __shfl_xor(s, o); q += __shfl_xor(q, o); }
    const float mean = s * (1.f / 256.f);
    const float var = q * (1.f / 256.f) - mean * mean;
    const float rstd = rsqrtf(var + 1e-5f);
    u16x4 ov;
#pragma unroll
    for (int j = 0; j < 4; ++j) {
        const int c = h * 256 + l * 4 + j;
        ov[j] = f2bf((f[j] - mean) * rstd * g[c] + b[c]);
    }
    *(u16x4*)(out + base) = ov;
}

// out[N,K](bf16) = in[K,N](f32)^T, dims % 32 == 0, block = 256 (32x8)
__global__ __launch_bounds__(256) void transpose_kernel(
    const float* __restrict__ in, u16* __restrict__ out, int K, int N)
{
    __shared__ u16 t[32][33];
    const int n0 = blockIdx.x * 32, k0 = blockIdx.y * 32;
    const int tx = threadIdx.x & 31, ty = threadIdx.x >> 5;
#pragma unroll
    for (int i = 0; i < 32; i += 8)
        t[ty + i][tx] = f2bf(in[(size_t)(k0 + ty + i) * N + (n0 + tx)]);
    __syncthreads();
#pragma unroll
    for (int i = 0; i < 32; i += 8)
        out[(size_t)(n0 + ty + i) * K + (k0 + tx)] = t[tx][ty + i];
}

// Wh1t[768][512](bf16): Wh1t[h*256+k][d] = wh1[h][d][k]
__global__ void gather_wh1t(const float* __restrict__ wh1, u16* __restrict__ out)
{
    const int idx = blockIdx.x * 256 + threadIdx.x;
    if (idx >= 768 * 512) return;
    const int d = idx & 511, j = idx >> 9;
    const int h = j >> 8, kk = j & 255;
    out[idx] = f2bf(wh1[((size_t)(h * 512 + d)) * 256 + kk]);
}

// Wh2t[3][896][256](bf16): Wh2t[h][o][k] = wh2[h][k][o]
__global__ void gather_wh2t(const float* __restrict__ wh2, u16* __restrict__ out)
{
    const int idx = blockIdx.x * 256 + threadIdx.x;
    if (idx >= 3 * 896 * 256) return;
    const int kk = idx & 255, t = idx >> 8;
    const int h = t / 896, o = t - h * 896;
    out[idx] = f2bf(wh2[((size_t)(h * 256 + kk)) * 896 + o]);
}

// parallel bias prep: 8 blocks; block b covers i in [b*64, b*64+64).
__global__ __launch_bounds__(256) void prep_bias_kernel(
    const float* __restrict__ b_in, const float* __restrict__ pos,
    const float* __restrict__ bv_sa, const float* __restrict__ wo_sa,
    const float* __restrict__ bo_sa,
    const float* __restrict__ bv_ca, const float* __restrict__ wo_ca,
    const float* __restrict__ bo_ca,
    float* __restrict__ bias_in, float* __restrict__ b_comb)
{
    __shared__ float psa[4][64], pca[4][64];
    const int ii = threadIdx.x & 63, kg = threadIdx.x >> 6;
    const int i = blockIdx.x * 64 + ii;
    float sa = 0.f, ca = 0.f;
    for (int k = kg; k < 512; k += 4) {
        sa += bv_sa[k] * wo_sa[(size_t)k * 512 + i];
        ca += bv_ca[k] * wo_ca[(size_t)k * 512 + i];
    }
    psa[kg][ii] = sa; pca[kg][ii] = ca;
    __syncthreads();
    if (kg == 0) {
        bias_in[i] = b_in[i] + pos[i];
        b_comb[i] = psa[0][ii] + psa[1][ii] + psa[2][ii] + psa[3][ii]
                  + pca[0][ii] + pca[1][ii] + pca[2][ii] + pca[3][ii]
                  + bo_sa[i] + bo_ca[i];
    }
}

extern "C" void kernel_launch(void* const* d_in, const int* in_sizes, int n_in,
                              void* d_out, int out_size, void* d_ws, size_t ws_size,
                              hipStream_t stream)
{
    const float* x      = (const float*)d_in[0];
    const float* w_in   = (const float*)d_in[1];
    const float* b_in   = (const float*)d_in[2];
    const float* pos    = (const float*)d_in[3];
    const float* ln1_g  = (const float*)d_in[4];
    const float* ln1_b  = (const float*)d_in[5];
    const float* wv_sa  = (const float*)d_in[6];
    const float* bv_sa  = (const float*)d_in[7];
    const float* wo_sa  = (const float*)d_in[8];
    const float* bo_sa  = (const float*)d_in[9];
    const float* wv_ca  = (const float*)d_in[12];
    const float* bv_ca  = (const float*)d_in[13];
    const float* wo_ca  = (const float*)d_in[14];
    const float* bo_ca  = (const float*)d_in[15];
    const float* ln3_g  = (const float*)d_in[16];
    const float* ln3_b  = (const float*)d_in[17];
    const float* w_ff1  = (const float*)d_in[18];
    const float* b_ff1  = (const float*)d_in[19];
    const float* w_ff2  = (const float*)d_in[20];
    const float* b_ff2  = (const float*)d_in[21];
    const float* lnoutg = (const float*)d_in[22];
    const float* lnoutb = (const float*)d_in[23];
    const float* wh1    = (const float*)d_in[24];
    const float* bh1    = (const float*)d_in[25];
    const float* lnh_g  = (const float*)d_in[26];
    const float* lnh_b  = (const float*)d_in[27];
    const float* wh2    = (const float*)d_in[28];
    const float* bh2    = (const float*)d_in[29];
    float* out = (float*)d_out;
    const int KBIG = 0x7fffffff;

    // ---- workspace layout (~70 MB, rewritten fully every call) ----
    char* wsp = (char*)d_ws;
    size_t off = 0;
    auto ALLOC = [&](size_t n) { char* r = wsp + off; off = (off + n + 255) & ~(size_t)255; return r; };
    u16* w_inT  = (u16*)ALLOC(512UL * 4096 * 2);
    u16* wff1t  = (u16*)ALLOC(2048UL * 512 * 2);
    u16* wff2t  = (u16*)ALLOC(512UL * 2048 * 2);
    u16* woT2   = (u16*)ALLOC(2UL * 512 * 512 * 2);  // [0]=woTca, [1]=woTsa
    u16* wv2b   = (u16*)ALLOC(2UL * 512 * 512 * 2);  // [0]=wv_ca, [1]=wv_sa
    u16* Wct    = (u16*)ALLOC(512UL * 1024 * 2);     // [n][k] k<512: ca, k>=512: sa
    u16* Wh1t   = (u16*)ALLOC(768UL * 512 * 2);
    u16* Wh2t   = (u16*)ALLOC(3UL * 896 * 256 * 2);
    float* bias_in = (float*)ALLOC(512 * 4);
    float* b_comb  = (float*)ALLOC(512 * 4);
    u16* h0   = (u16*)ALLOC(8192UL * 512 * 2);   // h0, later reused as h3
    u16* T    = (u16*)ALLOC(8192UL * 512 * 2);   // ln1 / ln3 / lnout output
    u16* hbuf = (u16*)ALLOC(8192UL * 512 * 2);   // h2
    u16* G    = (u16*)ALLOC(8192UL * 2048 * 2);  // FF intermediate; Z/Z2 alias
    u16* Z  = G;
    u16* Z2 = (u16*)((char*)G + 8192UL * 768 * 2);
    // split-K partial regions (alias buffers that are FREE at that stage):
    float* part1 = (float*)T;   // GEMM1: spans T+hbuf+G (3 x 16.78 MB) — all free
    float* part2 = (float*)G;   // attention: 2 x 16.78 MB in G — free
    const long PZS = 8192L * 512;

    // ---- weight prep ----
    cvt_f32_bf16<<<128, 256, 0, stream>>>(wv_ca, wv2b, 512 * 512 / 8);
    cvt_f32_bf16<<<128, 256, 0, stream>>>(wv_sa, wv2b + 512 * 512, 512 * 512 / 8);
    prep_bias_kernel<<<8, 256, 0, stream>>>(b_in, pos, bv_sa, wo_sa, bo_sa,
        bv_ca, wo_ca, bo_ca, bias_in, b_comb);
    transpose_kernel<<<dim3(16, 128), 256, 0, stream>>>(w_in, w_inT, 4096, 512);
    transpose_kernel<<<dim3(64, 16), 256, 0, stream>>>(w_ff1, wff1t, 512, 2048);
    transpose_kernel<<<dim3(16, 64), 256, 0, stream>>>(w_ff2, wff2t, 2048, 512);
    transpose_kernel<<<dim3(16, 16), 256, 0, stream>>>(wo_ca, woT2, 512, 512);
    transpose_kernel<<<dim3(16, 16), 256, 0, stream>>>(wo_sa, woT2 + 512 * 512, 512, 512);
    gather_wh1t<<<1536, 256, 0, stream>>>(wh1, Wh1t);
    gather_wh2t<<<2688, 256, 0, stream>>>(wh2, Wh2t);
    // Wct (z-batched): z=0 -> ca half (k<512), z=1 -> sa half (k>=512)
    gemm64<false, false, false, false><<<dim3(8, 4, 2), 256, 0, stream>>>(
        woT2, nullptr, KBIG, wv2b, nullptr, nullptr, 0, Wct,
        512, 512, 512, 1024, 512 * 512, 512 * 512, 0, 512, 0);

    // ---- main pipeline ----
    // GEMM1 split-K x3: partials, then reduce+bias
    gemm128<false, false, true, false, true><<<dim3(64, 4, 3), 256, 0, stream>>>(
        x, nullptr, KBIG, w_inT, nullptr, nullptr, 0, part1,
        4096, 4096, 4096, 512, 0, 0, 0, PZS, 1376);
    reduceK<3><<<4096, 256, 0, stream>>>(part1, PZS, bias_in, nullptr, h0);
    // T = ln1(h0)
    ln512_kernel<<<2048, 256, 0, stream>>>(h0, ln1_g, ln1_b, T);
    // attention split-K x2: [h0 | T] @ Wct -> partials; reduce fuses +b_comb +h0
    gemm128<false, false, false, false, true><<<dim3(64, 4, 2), 256, 0, stream>>>(
        h0, T, 512, Wct, nullptr, nullptr, 0, part2,
        1024, 512, 1024, 512, 0, 0, 0, PZS, 512);
    reduceK<2><<<4096, 256, 0, stream>>>(part2, PZS, b_comb, h0, hbuf);
    // T = ln3(h2)
    ln512_kernel<<<2048, 256, 0, stream>>>(hbuf, ln3_g, ln3_b, T);
    // G = gelu(T @ w_ff1 + b_ff1)   [8192, 2048]
    gemm128<true, false, false, false, false><<<dim3(64, 16), 256, 0, stream>>>(
        T, nullptr, KBIG, wff1t, b_ff1, nullptr, 0, G,
        512, 512, 512, 2048, 0, 0, 0, 0, 0);
    // h3(=h0) = h2 + G @ w_ff2 + b_ff2
    gemm64<false, true, false, false><<<dim3(128, 4), 256, 0, stream>>>(
        G, nullptr, KBIG, wff2t, b_ff2, hbuf, 512, h0,
        2048, 2048, 2048, 512, 0, 0, 0, 0, 0);
    // T = lnout(h3)
    ln512_kernel<<<2048, 256, 0, stream>>>(h0, lnoutg, lnoutb, T);
    // Z = gelu(T @ Wh1 + bh1)   [8192, 768]
    gemm64<true, false, false, false><<<dim3(128, 6), 256, 0, stream>>>(
        T, nullptr, KBIG, Wh1t, bh1, nullptr, 0, Z,
        512, 512, 512, 768, 0, 0, 0, 0, 0);
    // Z2 = per-head LN(Z)
    lnh_kernel<<<6144, 256, 0, stream>>>(Z, lnh_g, lnh_b, Z2);
    // out[:, z*896:(z+1)*896] = Z2[:, z*256:+256] @ wh2[z] + bh2[z]  (f32, z-batched)
    gemm128<false, false, false, true, false><<<dim3(64, 7, 3), 256, 0, stream>>>(
        Z2, nullptr, KBIG, Wh2t, bh2, nullptr, 0, out,
        256, 768, 256, 2688, 256, 896 * 256, 896, 896, 0);
}

// Round 15
// 422.127 us; speedup vs baseline: 1.0077x; 1.0077x over previous
//
#include <hip/hip_runtime.h>
#include <math.h>

// ---------------------------------------------------------------------------
// RFSQDraftModelWithProjection — f32 in / f32 out, bf16 MFMA compute.
// r15: r13 structure (64x128 tile, m-tile on blockIdx.x, counted vmcnt,
// AF32 depth-2 reg prefetch) + DEEP split-K using d_out as partial scratch
// (88 MB free until the final heads GEMM): GEMM1 x5, FF2 x2, attn x2 (in G).
// ---------------------------------------------------------------------------

typedef unsigned short u16;
typedef __attribute__((ext_vector_type(8))) short bf16x8;
typedef __attribute__((ext_vector_type(4))) float f32x4;
typedef __attribute__((ext_vector_type(8))) unsigned short u16x8;
typedef __attribute__((ext_vector_type(4))) unsigned short u16x4;

__device__ __forceinline__ float bf2f(u16 u){
    union { unsigned int i; float f; } x; x.i = ((unsigned int)u) << 16; return x.f;
}
__device__ __forceinline__ u16 f2bf(float f){
    union { float f; unsigned int i; } x; x.f = f;
    unsigned int r = x.i + 0x7fffu + ((x.i >> 16) & 1u);
    return (u16)(r >> 16);
}
__device__ __forceinline__ float gelu_exact(float v){
    return 0.5f * v * (1.0f + erff(v * 0.7071067811865475f));
}
#define GLOAD16(src, dst) __builtin_amdgcn_global_load_lds( \
    (const __attribute__((address_space(1))) void*)(src),   \
    (__attribute__((address_space(3))) void*)(dst), 16, 0, 0)
#define SCHED0 __builtin_amdgcn_sched_barrier(0)

// ---------------------------------------------------------------------------
// gemm64: C[M,N] = A[M,K] @ B[K,N] (+bias +res, opt GELU). 64x128 tile,
// BK=32, 4 waves (2x2 of 32x64), 8 MFMA/step, counted-vmcnt double buffer.
// blockIdx.x = m-tile (XCD L2 A-reuse), blockIdx.y = n-tile.
// AF32: f32 A, depth-2 register prefetch. A2/ksplit: concat second A source.
// PART: blockIdx.z = k-chunk [z*kch, min(+kch,K)); raw f32 partials at
// Cout + z*czs. Else blockIdx.z = batch via azs/bzs/biaszs/czs strides.
// ---------------------------------------------------------------------------
template<bool GELU, bool RES, bool AF32, bool OUTF32, bool PART>
__global__ __launch_bounds__(256) void gemm64(
    const void* __restrict__ A, const void* __restrict__ A2, int ksplit,
    const u16* __restrict__ Bt, const float* __restrict__ bias,
    const u16* __restrict__ res, int ldr,
    void* __restrict__ Cout, int K, int lda, int ldb, int ldc,
    long azs, long bzs, int biaszs, long czs, int kch)
{
    __shared__ __align__(16) u16 As[2][64 * 32];
    __shared__ __align__(16) u16 Bs[2][128 * 32];
    const int tid = threadIdx.x;
    const int w = tid >> 6, l = tid & 63;
    const int wr = w >> 1, wc = w & 1;
    const int m0 = blockIdx.x * 64, n0 = blockIdx.y * 128;
    const int z = blockIdx.z;
    int kbeg = 0, kend = K;
    if (PART) { kbeg = z * kch; kend = min(kbeg + kch, K); }
    const u16* A16 = (const u16*)A + (PART ? 0 : (size_t)z * azs);
    const float* Af = (const float*)A;
    const u16* BtZ = Bt + (PART ? 0 : (size_t)z * bzs);

    f32x4 acc[2][4];
#pragma unroll
    for (int i = 0; i < 2; ++i)
#pragma unroll
        for (int j = 0; j < 4; ++j) acc[i][j] = (f32x4){0.f, 0.f, 0.f, 0.f};

    auto stageB = [&](int buf, int k0) {
#pragma unroll
        for (int j = 0; j < 2; ++j) {
            const u16* gb = BtZ + (size_t)(n0 + (w * 2 + j) * 16 + (l >> 2)) * ldb
                          + k0 + (l & 3) * 8;
            GLOAD16(gb, &Bs[buf][(w * 2 + j) * 512]);
        }
    };
    auto stageA16 = [&](int buf, int k0) {
        const u16* base = (k0 >= ksplit) ? ((const u16*)A2 + (k0 - ksplit)) : (A16 + k0);
        const u16* ga = base + (size_t)(m0 + w * 16 + (l >> 2)) * lda + (l & 3) * 8;
        GLOAD16(ga, &As[buf][w * 512]);
    };
    auto loadA = [&](int k0, float4& p0, float4& p1) {
        const float* g = Af + (size_t)(m0 + (tid >> 2)) * lda + k0 + (tid & 3) * 8;
        p0 = *(const float4*)g; p1 = *(const float4*)(g + 4);
    };
    auto writeA = [&](const float4& p0, const float4& p1, int buf) {
        u16x8 v;
        v[0] = f2bf(p0.x); v[1] = f2bf(p0.y); v[2] = f2bf(p0.z); v[3] = f2bf(p0.w);
        v[4] = f2bf(p1.x); v[5] = f2bf(p1.y); v[6] = f2bf(p1.z); v[7] = f2bf(p1.w);
        *(u16x8*)&As[buf][(tid >> 2) * 32 + (tid & 3) * 8] = v;
    };
    int cur = 0;
    auto compute = [&]() {
        bf16x8 a[2], b[4];
#pragma unroll
        for (int i = 0; i < 2; ++i)
            a[i] = *(const bf16x8*)&As[cur][(wr * 32 + i * 16 + (l & 15)) * 32 + (l >> 4) * 8];
#pragma unroll
        for (int j = 0; j < 4; ++j)
            b[j] = *(const bf16x8*)&Bs[cur][(wc * 64 + j * 16 + (l & 15)) * 32 + (l >> 4) * 8];
#pragma unroll
        for (int i = 0; i < 2; ++i)
#pragma unroll
            for (int j = 0; j < 4; ++j)
                acc[i][j] = __builtin_amdgcn_mfma_f32_16x16x32_bf16(a[i], b[j], acc[i][j], 0, 0, 0);
    };

    const int nt = (kend - kbeg) >> 5;
    if (AF32) {
        float4 a0, a1, b0, b1;
        loadA(kbeg, a0, a1);
        stageB(0, kbeg);
        if (nt > 1) loadA(kbeg + 32, b0, b1);
        if (nt > 1) asm volatile("s_waitcnt vmcnt(4)" ::: "memory");
        else        asm volatile("s_waitcnt vmcnt(2)" ::: "memory");
        writeA(a0, a1, 0);
        asm volatile("s_waitcnt lgkmcnt(0)" ::: "memory");
        auto stepA = [&](int t, float4& w0, float4& w1, float4& l0, float4& l1) {
            const bool ldA = (t + 2) < nt;
            const bool stB = (t + 1) < nt;
            if (ldA) loadA(kbeg + ((t + 2) << 5), l0, l1);
            if (stB) stageB(cur ^ 1, kbeg + ((t + 1) << 5));
            if (ldA)      asm volatile("s_waitcnt vmcnt(4)" ::: "memory");
            else if (stB) asm volatile("s_waitcnt vmcnt(2)" ::: "memory");
            else          asm volatile("s_waitcnt vmcnt(0)" ::: "memory");
            SCHED0;
            __builtin_amdgcn_s_barrier();
            SCHED0;
            compute();
            if (stB) writeA(w0, w1, cur ^ 1);
            asm volatile("s_waitcnt lgkmcnt(0)" ::: "memory");
            SCHED0;
            __builtin_amdgcn_s_barrier();
            SCHED0;
            cur ^= 1;
        };
        int t = 0;
        while (t + 2 <= nt) {
            stepA(t,     b0, b1, a0, a1);
            stepA(t + 1, a0, a1, b0, b1);
            t += 2;
        }
        if (t < nt) stepA(t, b0, b1, a0, a1);
    } else {
        stageA16(0, kbeg);
        stageB(0, kbeg);
        for (int t = 0; t < nt; ++t) {
            const bool more = (t + 1) < nt;
            if (more) {
                const int kn = kbeg + ((t + 1) << 5);
                stageA16(cur ^ 1, kn);
                stageB(cur ^ 1, kn);
            }
            if (more) asm volatile("s_waitcnt vmcnt(3)" ::: "memory");
            else      asm volatile("s_waitcnt vmcnt(0)" ::: "memory");
            SCHED0;
            __builtin_amdgcn_s_barrier();
            SCHED0;
            compute();
            asm volatile("" ::: "memory");
            SCHED0;
            __builtin_amdgcn_s_barrier();
            SCHED0;
            cur ^= 1;
        }
    }

    // epilogue: C/D layout col = l&15, row = (l>>4)*4 + r  [m89/m91]
    float* cF = (float*)Cout + (size_t)z * czs;
    u16*   cH = (u16*)Cout + (size_t)z * czs;
    const float* biasZ = (!PART && bias) ? bias + (size_t)z * biaszs : nullptr;
#pragma unroll
    for (int i = 0; i < 2; ++i) {
#pragma unroll
        for (int j = 0; j < 4; ++j) {
            const int col = n0 + wc * 64 + j * 16 + (l & 15);
            const int rowb = m0 + wr * 32 + i * 16 + (l >> 4) * 4;
#pragma unroll
            for (int r = 0; r < 4; ++r) {
                const int row = rowb + r;
                float v = acc[i][j][r];
                if (PART) {
                    cF[(size_t)row * ldc + col] = v;
                } else {
                    if (biasZ) v += biasZ[col];
                    if (RES) v += bf2f(res[(size_t)row * ldr + col]);
                    if (GELU) v = gelu_exact(v);
                    if (OUTF32) cF[(size_t)row * ldc + col] = v;
                    else        cH[(size_t)row * ldc + col] = f2bf(v);
                }
            }
        }
    }
}

// split-K reduce over [8192,512]: out = bf16(sum_p part[p] + bias (+res))
template<int NP>
__global__ __launch_bounds__(256) void reduceK(
    const float* __restrict__ part, long pzs, const float* __restrict__ bias,
    const u16* __restrict__ res, u16* __restrict__ out)
{
    const int idx = (blockIdx.x * 256 + threadIdx.x) * 4;
    const int col = idx & 511;
    float4 s = *(const float4*)(part + idx);
#pragma unroll
    for (int p = 1; p < NP; ++p) {
        const float4 v = *(const float4*)(part + (size_t)p * pzs + idx);
        s.x += v.x; s.y += v.y; s.z += v.z; s.w += v.w;
    }
    const float4 b = *(const float4*)(bias + col);
    s.x += b.x; s.y += b.y; s.z += b.z; s.w += b.w;
    if (res) {
        const u16x4 r = *(const u16x4*)(res + idx);
        s.x += bf2f(r[0]); s.y += bf2f(r[1]); s.z += bf2f(r[2]); s.w += bf2f(r[3]);
    }
    u16x4 o;
    o[0] = f2bf(s.x); o[1] = f2bf(s.y); o[2] = f2bf(s.z); o[3] = f2bf(s.w);
    *(u16x4*)(out + idx) = o;
}

// f32 -> bf16 bulk convert, 8 elems/thread
__global__ __launch_bounds__(256) void cvt_f32_bf16(
    const float* __restrict__ in, u16* __restrict__ out, int n8)
{
    const int i = blockIdx.x * 256 + threadIdx.x;
    if (i >= n8) return;
    const float4* p = (const float4*)in + (size_t)i * 2;
    const float4 a = p[0], b = p[1];
    u16x8 v;
    v[0] = f2bf(a.x); v[1] = f2bf(a.y); v[2] = f2bf(a.z); v[3] = f2bf(a.w);
    v[4] = f2bf(b.x); v[5] = f2bf(b.y); v[6] = f2bf(b.z); v[7] = f2bf(b.w);
    *(u16x8*)(out + (size_t)i * 8) = v;
}

// LayerNorm over 512 cols (bf16 in/out, f32 g/b), one wave per row
__global__ __launch_bounds__(256) void ln512_kernel(
    const u16* __restrict__ in, const float* __restrict__ g,
    const float* __restrict__ b, u16* __restrict__ out)
{
    const int wid = threadIdx.x >> 6, l = threadIdx.x & 63;
    const size_t row = (size_t)blockIdx.x * 4 + wid;
    u16x8 v = *(const u16x8*)(in + row * 512 + l * 8);
    float f[8], s = 0.f, q = 0.f;
#pragma unroll
    for (int j = 0; j < 8; ++j) { f[j] = bf2f(v[j]); s += f[j]; q += f[j] * f[j]; }
#pragma unroll
    for (int o = 32; o > 0; o >>= 1) { s += __shfl_xor(s, o); q += __shfl_xor(q, o); }
    const float mean = s * (1.f / 512.f);
    const float var = q * (1.f / 512.f) - mean * mean;
    const float rstd = rsqrtf(var + 1e-5f);
    u16x8 ov;
#pragma unroll
    for (int j = 0; j < 8; ++j) {
        const int c = l * 8 + j;
        ov[j] = f2bf((f[j] - mean) * rstd * g[c] + b[c]);
    }
    *(u16x8*)(out + row * 512 + l * 8) = ov;
}

// per-head LN over 256 (rows are [8192,768], heads of 256), wave per (row,head)
__global__ __launch_bounds__(256) void lnh_kernel(
    const u16* __restrict__ in, const float* __restrict__ g,
    const float* __restrict__ b, u16* __restrict__ out)
{
    const int wid = threadIdx.x >> 6, l = threadIdx.x & 63;
    const int unit = blockIdx.x * 4 + wid;        // unit = h*8192 + row
    const int h = unit >> 13, row = unit & 8191;
    const size_t base = (size_t)row * 768 + h * 256 + l * 4;
    u16x4 v = *(const u16x4*)(in + base);
    float f[4], s = 0.f, q = 0.f;
#pragma unroll
    for (int j = 0; j < 4; ++j) { f[j] = bf2f(v[j]); s += f[j]; q += f[j] * f[j]; }
#pragma unroll
    for (int o = 32; o > 0; o >>= 1) { s += __shfl_xor(s, o); q += __shfl_xor(q, o); }
    const float mean = s * (1.f / 256.f);
    const float var = q * (1.f / 256.f) - mean * mean;
    const float rstd = rsqrtf(var + 1e-5f);
    u16x4 ov;
#pragma unroll
    for (int j = 0; j < 4; ++j) {
        const int c = h * 256 + l * 4 + j;
        ov[j] = f2bf((f[j] - mean) * rstd * g[c] + b[c]);
    }
    *(u16x4*)(out + base) = ov;
}

// out[N,K](bf16) = in[K,N](f32)^T, dims % 32 == 0, block = 256 (32x8)
__global__ __launch_bounds__(256) void transpose_kernel(
    const float* __restrict__ in, u16* __restrict__ out, int K, int N)
{
    __shared__ u16 t[32][33];
    const int n0 = blockIdx.x * 32, k0 = blockIdx.y * 32;
    const int tx = threadIdx.x & 31, ty = threadIdx.x >> 5;
#pragma unroll
    for (int i = 0; i < 32; i += 8)
        t[ty + i][tx] = f2bf(in[(size_t)(k0 + ty + i) * N + (n0 + tx)]);
    __syncthreads();
#pragma unroll
    for (int i = 0; i < 32; i += 8)
        out[(size_t)(n0 + ty + i) * K + (k0 + tx)] = t[tx][ty + i];
}

// Wh1t[768][512](bf16): Wh1t[h*256+k][d] = wh1[h][d][k]
__global__ void gather_wh1t(const float* __restrict__ wh1, u16* __restrict__ out)
{
    const int idx = blockIdx.x * 256 + threadIdx.x;
    if (idx >= 768 * 512) return;
    const int d = idx & 511, j = idx >> 9;
    const int h = j >> 8, kk = j & 255;
    out[idx] = f2bf(wh1[((size_t)(h * 512 + d)) * 256 + kk]);
}

// Wh2t[3][896][256](bf16): Wh2t[h][o][k] = wh2[h][k][o]
__global__ void gather_wh2t(const float* __restrict__ wh2, u16* __restrict__ out)
{
    const int idx = blockIdx.x * 256 + threadIdx.x;
    if (idx >= 3 * 896 * 256) return;
    const int kk = idx & 255, t = idx >> 8;
    const int h = t / 896, o = t - h * 896;
    out[idx] = f2bf(wh2[((size_t)(h * 256 + kk)) * 896 + o]);
}

// parallel bias prep: 8 blocks; block b covers i in [b*64, b*64+64).
__global__ __launch_bounds__(256) void prep_bias_kernel(
    const float* __restrict__ b_in, const float* __restrict__ pos,
    const float* __restrict__ bv_sa, const float* __restrict__ wo_sa,
    const float* __restrict__ bo_sa,
    const float* __restrict__ bv_ca, const float* __restrict__ wo_ca,
    const float* __restrict__ bo_ca,
    float* __restrict__ bias_in, float* __restrict__ b_comb)
{
    __shared__ float psa[4][64], pca[4][64];
    const int ii = threadIdx.x & 63, kg = threadIdx.x >> 6;
    const int i = blockIdx.x * 64 + ii;
    float sa = 0.f, ca = 0.f;
    for (int k = kg; k < 512; k += 4) {
        sa += bv_sa[k] * wo_sa[(size_t)k * 512 + i];
        ca += bv_ca[k] * wo_ca[(size_t)k * 512 + i];
    }
    psa[kg][ii] = sa; pca[kg][ii] = ca;
    __syncthreads();
    if (kg == 0) {
        bias_in[i] = b_in[i] + pos[i];
        b_comb[i] = psa[0][ii] + psa[1][ii] + psa[2][ii] + psa[3][ii]
                  + pca[0][ii] + pca[1][ii] + pca[2][ii] + pca[3][ii]
                  + bo_sa[i] + bo_ca[i];
    }
}

extern "C" void kernel_launch(void* const* d_in, const int* in_sizes, int n_in,
                              void* d_out, int out_size, void* d_ws, size_t ws_size,
                              hipStream_t stream)
{
    const float* x      = (const float*)d_in[0];
    const float* w_in   = (const float*)d_in[1];
    const float* b_in   = (const float*)d_in[2];
    const float* pos    = (const float*)d_in[3];
    const float* ln1_g  = (const float*)d_in[4];
    const float* ln1_b  = (const float*)d_in[5];
    const float* wv_sa  = (const float*)d_in[6];
    const float* bv_sa  = (const float*)d_in[7];
    const float* wo_sa  = (const float*)d_in[8];
    const float* bo_sa  = (const float*)d_in[9];
    const float* wv_ca  = (const float*)d_in[12];
    const float* bv_ca  = (const float*)d_in[13];
    const float* wo_ca  = (const float*)d_in[14];
    const float* bo_ca  = (const float*)d_in[15];
    const float* ln3_g  = (const float*)d_in[16];
    const float* ln3_b  = (const float*)d_in[17];
    const float* w_ff1  = (const float*)d_in[18];
    const float* b_ff1  = (const float*)d_in[19];
    const float* w_ff2  = (const float*)d_in[20];
    const float* b_ff2  = (const float*)d_in[21];
    const float* lnoutg = (const float*)d_in[22];
    const float* lnoutb = (const float*)d_in[23];
    const float* wh1    = (const float*)d_in[24];
    const float* bh1    = (const float*)d_in[25];
    const float* lnh_g  = (const float*)d_in[26];
    const float* lnh_b  = (const float*)d_in[27];
    const float* wh2    = (const float*)d_in[28];
    const float* bh2    = (const float*)d_in[29];
    float* out = (float*)d_out;
    const int KBIG = 0x7fffffff;

    // ---- workspace layout (~70 MB, rewritten fully every call) ----
    char* wsp = (char*)d_ws;
    size_t off = 0;
    auto ALLOC = [&](size_t n) { char* r = wsp + off; off = (off + n + 255) & ~(size_t)255; return r; };
    u16* w_inT  = (u16*)ALLOC(512UL * 4096 * 2);
    u16* wff1t  = (u16*)ALLOC(2048UL * 512 * 2);
    u16* wff2t  = (u16*)ALLOC(512UL * 2048 * 2);
    u16* woT2   = (u16*)ALLOC(2UL * 512 * 512 * 2);  // [0]=woTca, [1]=woTsa
    u16* wv2b   = (u16*)ALLOC(2UL * 512 * 512 * 2);  // [0]=wv_ca, [1]=wv_sa
    u16* Wct    = (u16*)ALLOC(512UL * 1024 * 2);     // [n][k] k<512: ca, k>=512: sa
    u16* Wh1t   = (u16*)ALLOC(768UL * 512 * 2);
    u16* Wh2t   = (u16*)ALLOC(3UL * 896 * 256 * 2);
    float* bias_in = (float*)ALLOC(512 * 4);
    float* b_comb  = (float*)ALLOC(512 * 4);
    u16* h0   = (u16*)ALLOC(8192UL * 512 * 2);   // h0, later reused as h3
    u16* T    = (u16*)ALLOC(8192UL * 512 * 2);   // ln1 / ln3 / lnout output
    u16* hbuf = (u16*)ALLOC(8192UL * 512 * 2);   // h2
    u16* G    = (u16*)ALLOC(8192UL * 2048 * 2);  // FF intermediate; Z/Z2 alias
    u16* Z  = G;
    u16* Z2 = (u16*)((char*)G + 8192UL * 768 * 2);
    // split-K partials: d_out (88 MB, free until final heads GEMM) + G.
    float* partO = out;         // GEMM1 x5 (84 MB), later FF2 x2 (33.5 MB)
    float* part2 = (float*)G;   // attention x2 (33.5 MB in G — free then)
    const long PZS = 8192L * 512;

    // ---- weight prep ----
    cvt_f32_bf16<<<128, 256, 0, stream>>>(wv_ca, wv2b, 512 * 512 / 8);
    cvt_f32_bf16<<<128, 256, 0, stream>>>(wv_sa, wv2b + 512 * 512, 512 * 512 / 8);
    prep_bias_kernel<<<8, 256, 0, stream>>>(b_in, pos, bv_sa, wo_sa, bo_sa,
        bv_ca, wo_ca, bo_ca, bias_in, b_comb);
    transpose_kernel<<<dim3(16, 128), 256, 0, stream>>>(w_in, w_inT, 4096, 512);
    transpose_kernel<<<dim3(64, 16), 256, 0, stream>>>(w_ff1, wff1t, 512, 2048);
    transpose_kernel<<<dim3(16, 64), 256, 0, stream>>>(w_ff2, wff2t, 2048, 512);
    transpose_kernel<<<dim3(16, 16), 256, 0, stream>>>(wo_ca, woT2, 512, 512);
    transpose_kernel<<<dim3(16, 16), 256, 0, stream>>>(wo_sa, woT2 + 512 * 512, 512, 512);
    gather_wh1t<<<1536, 256, 0, stream>>>(wh1, Wh1t);
    gather_wh2t<<<2688, 256, 0, stream>>>(wh2, Wh2t);
    // Wct (z-batched): z=0 -> ca half (k<512), z=1 -> sa half (k>=512)
    gemm64<false, false, false, false, false><<<dim3(8, 4, 2), 256, 0, stream>>>(
        woT2, nullptr, KBIG, wv2b, nullptr, nullptr, 0, Wct,
        512, 512, 512, 1024, 512 * 512, 512 * 512, 0, 512, 0);

    // ---- main pipeline ----
    // GEMM1 split-K x5 (kch=832: chunks 832x4 + 768) -> partials in d_out
    gemm64<false, false, true, false, true><<<dim3(128, 4, 5), 256, 0, stream>>>(
        x, nullptr, KBIG, w_inT, nullptr, nullptr, 0, partO,
        4096, 4096, 4096, 512, 0, 0, 0, PZS, 832);
    reduceK<5><<<4096, 256, 0, stream>>>(partO, PZS, bias_in, nullptr, h0);
    // T = ln1(h0)
    ln512_kernel<<<2048, 256, 0, stream>>>(h0, ln1_g, ln1_b, T);
    // attention split-K x2: [h0 | T] @ Wct -> partials in G; reduce fuses
    // +b_comb +h0 residual -> h2 (hbuf)
    gemm64<false, false, false, false, true><<<dim3(128, 4, 2), 256, 0, stream>>>(
        h0, T, 512, Wct, nullptr, nullptr, 0, part2,
        1024, 512, 1024, 512, 0, 0, 0, PZS, 512);
    reduceK<2><<<4096, 256, 0, stream>>>(part2, PZS, b_comb, h0, hbuf);
    // T = ln3(h2)
    ln512_kernel<<<2048, 256, 0, stream>>>(hbuf, ln3_g, ln3_b, T);
    // G = gelu(T @ w_ff1 + b_ff1)   [8192, 2048]
    gemm64<true, false, false, false, false><<<dim3(128, 16), 256, 0, stream>>>(
        T, nullptr, KBIG, wff1t, b_ff1, nullptr, 0, G,
        512, 512, 512, 2048, 0, 0, 0, 0, 0);
    // FF2 split-K x2 (kch=1024) -> partials in d_out; reduce fuses +b_ff2 +h2
    gemm64<false, false, false, false, true><<<dim3(128, 4, 2), 256, 0, stream>>>(
        G, nullptr, KBIG, wff2t, nullptr, nullptr, 0, partO,
        2048, 2048, 2048, 512, 0, 0, 0, PZS, 1024);
    reduceK<2><<<4096, 256, 0, stream>>>(partO, PZS, b_ff2, hbuf, h0);
    // T = lnout(h3)
    ln512_kernel<<<2048, 256, 0, stream>>>(h0, lnoutg, lnoutb, T);
    // Z = gelu(T @ Wh1 + bh1)   [8192, 768]
    gemm64<true, false, false, false, false><<<dim3(128, 6), 256, 0, stream>>>(
        T, nullptr, KBIG, Wh1t, bh1, nullptr, 0, Z,
        512, 512, 512, 768, 0, 0, 0, 0, 0);
    // Z2 = per-head LN(Z)
    lnh_kernel<<<6144, 256, 0, stream>>>(Z, lnh_g, lnh_b, Z2);
    // out[:, z*896:(z+1)*896] = Z2[:, z*256:+256] @ wh2[z] + bh2[z]
    // (f32, z-batched; overwrites ALL partial scratch in d_out)
    gemm64<false, false, false, true, false><<<dim3(128, 7, 3), 256, 0, stream>>>(
        Z2, nullptr, KBIG, Wh2t, bh2, nullptr, 0, out,
        256, 768, 256, 2688, 256, 896 * 256, 896, 896, 0);
}

// Round 16
// 386.023 us; speedup vs baseline: 1.1019x; 1.0935x over previous
//
#include <hip/hip_runtime.h>
#include <math.h>

// ---------------------------------------------------------------------------
// RFSQDraftModelWithProjection — f32 in / f32 out, bf16 MFMA compute.
// r16: r13 GEMM config (64x128 tile, m-on-x XCD A-reuse, counted vmcnt,
// GEMM1 split-K x3) + fused reduce+LayerNorm (reduceLN512, kills 3 LN
// dispatches and ~50 MB traffic) + sigmoid-form fast GELU (1 v_exp).
// All split-K partials live in d_out (free until the final heads GEMM).
// ---------------------------------------------------------------------------

typedef unsigned short u16;
typedef __attribute__((ext_vector_type(8))) short bf16x8;
typedef __attribute__((ext_vector_type(4))) float f32x4;
typedef __attribute__((ext_vector_type(8))) unsigned short u16x8;
typedef __attribute__((ext_vector_type(4))) unsigned short u16x4;

__device__ __forceinline__ float bf2f(u16 u){
    union { unsigned int i; float f; } x; x.i = ((unsigned int)u) << 16; return x.f;
}
__device__ __forceinline__ u16 f2bf(float f){
    union { float f; unsigned int i; } x; x.f = f;
    unsigned int r = x.i + 0x7fffu + ((x.i >> 16) & 1u);
    return (u16)(r >> 16);
}
// tanh-form GELU as x*sigmoid(2t), t = 0.79788456(x + 0.044715 x^3).
// max |diff vs erf-GELU| ~3e-3 — far inside the bf16 threshold budget.
__device__ __forceinline__ float gelu_fast(float v){
    const float u = 1.5957691216f * v * (1.0f + 0.044715f * v * v);
    const float e = __expf(u);
    return v * (1.0f - 1.0f / (e + 1.0f));   // inf-safe
}
#define GLOAD16(src, dst) __builtin_amdgcn_global_load_lds( \
    (const __attribute__((address_space(1))) void*)(src),   \
    (__attribute__((address_space(3))) void*)(dst), 16, 0, 0)
#define SCHED0 __builtin_amdgcn_sched_barrier(0)

// ---------------------------------------------------------------------------
// gemm64: C[M,N] = A[M,K] @ B[K,N] (+bias +res, opt GELU). 64x128 tile,
// BK=32, 4 waves, 8 MFMA/step, counted-vmcnt double buffer.
// blockIdx.x = m-tile (same-m blocks land on one XCD: gridDim.x % 8 == 0),
// blockIdx.y = n-tile.  AF32: f32 A with depth-2 register prefetch.
// A2/ksplit: concat second A source at k=ksplit.  PART: blockIdx.z = k-chunk,
// raw f32 partials at Cout + z*czs.  Else z = batch via strides.
// ---------------------------------------------------------------------------
template<bool GELU, bool RES, bool AF32, bool OUTF32, bool PART>
__global__ __launch_bounds__(256) void gemm64(
    const void* __restrict__ A, const void* __restrict__ A2, int ksplit,
    const u16* __restrict__ Bt, const float* __restrict__ bias,
    const u16* __restrict__ res, int ldr,
    void* __restrict__ Cout, int K, int lda, int ldb, int ldc,
    long azs, long bzs, int biaszs, long czs, int kch)
{
    __shared__ __align__(16) u16 As[2][64 * 32];
    __shared__ __align__(16) u16 Bs[2][128 * 32];
    const int tid = threadIdx.x;
    const int w = tid >> 6, l = tid & 63;
    const int wr = w >> 1, wc = w & 1;
    const int m0 = blockIdx.x * 64, n0 = blockIdx.y * 128;
    const int z = blockIdx.z;
    int kbeg = 0, kend = K;
    if (PART) { kbeg = z * kch; kend = min(kbeg + kch, K); }
    const u16* A16 = (const u16*)A + (PART ? 0 : (size_t)z * azs);
    const float* Af = (const float*)A;
    const u16* BtZ = Bt + (PART ? 0 : (size_t)z * bzs);

    f32x4 acc[2][4];
#pragma unroll
    for (int i = 0; i < 2; ++i)
#pragma unroll
        for (int j = 0; j < 4; ++j) acc[i][j] = (f32x4){0.f, 0.f, 0.f, 0.f};

    auto stageB = [&](int buf, int k0) {
#pragma unroll
        for (int j = 0; j < 2; ++j) {
            const u16* gb = BtZ + (size_t)(n0 + (w * 2 + j) * 16 + (l >> 2)) * ldb
                          + k0 + (l & 3) * 8;
            GLOAD16(gb, &Bs[buf][(w * 2 + j) * 512]);
        }
    };
    auto stageA16 = [&](int buf, int k0) {
        const u16* base = (k0 >= ksplit) ? ((const u16*)A2 + (k0 - ksplit)) : (A16 + k0);
        const u16* ga = base + (size_t)(m0 + w * 16 + (l >> 2)) * lda + (l & 3) * 8;
        GLOAD16(ga, &As[buf][w * 512]);
    };
    auto loadA = [&](int k0, float4& p0, float4& p1) {
        const float* g = Af + (size_t)(m0 + (tid >> 2)) * lda + k0 + (tid & 3) * 8;
        p0 = *(const float4*)g; p1 = *(const float4*)(g + 4);
    };
    auto writeA = [&](const float4& p0, const float4& p1, int buf) {
        u16x8 v;
        v[0] = f2bf(p0.x); v[1] = f2bf(p0.y); v[2] = f2bf(p0.z); v[3] = f2bf(p0.w);
        v[4] = f2bf(p1.x); v[5] = f2bf(p1.y); v[6] = f2bf(p1.z); v[7] = f2bf(p1.w);
        *(u16x8*)&As[buf][(tid >> 2) * 32 + (tid & 3) * 8] = v;
    };
    int cur = 0;
    auto compute = [&]() {
        bf16x8 a[2], b[4];
#pragma unroll
        for (int i = 0; i < 2; ++i)
            a[i] = *(const bf16x8*)&As[cur][(wr * 32 + i * 16 + (l & 15)) * 32 + (l >> 4) * 8];
#pragma unroll
        for (int j = 0; j < 4; ++j)
            b[j] = *(const bf16x8*)&Bs[cur][(wc * 64 + j * 16 + (l & 15)) * 32 + (l >> 4) * 8];
#pragma unroll
        for (int i = 0; i < 2; ++i)
#pragma unroll
            for (int j = 0; j < 4; ++j)
                acc[i][j] = __builtin_amdgcn_mfma_f32_16x16x32_bf16(a[i], b[j], acc[i][j], 0, 0, 0);
    };

    const int nt = (kend - kbeg) >> 5;
    if (AF32) {
        float4 a0, a1, b0, b1;
        loadA(kbeg, a0, a1);
        stageB(0, kbeg);
        if (nt > 1) loadA(kbeg + 32, b0, b1);
        if (nt > 1) asm volatile("s_waitcnt vmcnt(4)" ::: "memory");
        else        asm volatile("s_waitcnt vmcnt(2)" ::: "memory");
        writeA(a0, a1, 0);
        asm volatile("s_waitcnt lgkmcnt(0)" ::: "memory");
        auto stepA = [&](int t, float4& w0, float4& w1, float4& l0, float4& l1) {
            const bool ldA = (t + 2) < nt;
            const bool stB = (t + 1) < nt;
            if (ldA) loadA(kbeg + ((t + 2) << 5), l0, l1);
            if (stB) stageB(cur ^ 1, kbeg + ((t + 1) << 5));
            if (ldA)      asm volatile("s_waitcnt vmcnt(4)" ::: "memory");
            else if (stB) asm volatile("s_waitcnt vmcnt(2)" ::: "memory");
            else          asm volatile("s_waitcnt vmcnt(0)" ::: "memory");
            SCHED0;
            __builtin_amdgcn_s_barrier();
            SCHED0;
            compute();
            if (stB) writeA(w0, w1, cur ^ 1);
            asm volatile("s_waitcnt lgkmcnt(0)" ::: "memory");
            SCHED0;
            __builtin_amdgcn_s_barrier();
            SCHED0;
            cur ^= 1;
        };
        int t = 0;
        while (t + 2 <= nt) {
            stepA(t,     b0, b1, a0, a1);
            stepA(t + 1, a0, a1, b0, b1);
            t += 2;
        }
        if (t < nt) stepA(t, b0, b1, a0, a1);
    } else {
        stageA16(0, kbeg);
        stageB(0, kbeg);
        for (int t = 0; t < nt; ++t) {
            const bool more = (t + 1) < nt;
            if (more) {
                const int kn = kbeg + ((t + 1) << 5);
                stageA16(cur ^ 1, kn);
                stageB(cur ^ 1, kn);
            }
            if (more) asm volatile("s_waitcnt vmcnt(3)" ::: "memory");
            else      asm volatile("s_waitcnt vmcnt(0)" ::: "memory");
            SCHED0;
            __builtin_amdgcn_s_barrier();
            SCHED0;
            compute();
            asm volatile("" ::: "memory");
            SCHED0;
            __builtin_amdgcn_s_barrier();
            SCHED0;
            cur ^= 1;
        }
    }

    // epilogue: C/D layout col = l&15, row = (l>>4)*4 + r  [m89/m91]
    float* cF = (float*)Cout + (size_t)z * czs;
    u16*   cH = (u16*)Cout + (size_t)z * czs;
    const float* biasZ = (!PART && bias) ? bias + (size_t)z * biaszs : nullptr;
#pragma unroll
    for (int i = 0; i < 2; ++i) {
#pragma unroll
        for (int j = 0; j < 4; ++j) {
            const int col = n0 + wc * 64 + j * 16 + (l & 15);
            const int rowb = m0 + wr * 32 + i * 16 + (l >> 4) * 4;
#pragma unroll
            for (int r = 0; r < 4; ++r) {
                const int row = rowb + r;
                float v = acc[i][j][r];
                if (PART) {
                    cF[(size_t)row * ldc + col] = v;
                } else {
                    if (biasZ) v += biasZ[col];
                    if (RES) v += bf2f(res[(size_t)row * ldr + col]);
                    if (GELU) v = gelu_fast(v);
                    if (OUTF32) cF[(size_t)row * ldc + col] = v;
                    else        cH[(size_t)row * ldc + col] = f2bf(v);
                }
            }
        }
    }
}

// ---------------------------------------------------------------------------
// reduceLN512: fused split-K reduce + bias (+res) -> optional bf16 H-write,
// then row LayerNorm (512 cols, f32 stats) -> bf16 T-write.
// One wave per row (8 cols/lane). Grid 2048 x 256.
// ---------------------------------------------------------------------------
template<int NP, bool RES, bool WRITEH>
__global__ __launch_bounds__(256) void reduceLN512(
    const float* __restrict__ part, long pzs, const float* __restrict__ bias,
    const u16* __restrict__ res, const float* __restrict__ g,
    const float* __restrict__ b, u16* __restrict__ outH, u16* __restrict__ outT)
{
    const int wid = threadIdx.x >> 6, l = threadIdx.x & 63;
    const size_t row = (size_t)blockIdx.x * 4 + wid;
    const size_t base = row * 512 + l * 8;
    float f[8];
    {
        const float4 p0 = *(const float4*)(part + base);
        const float4 p1 = *(const float4*)(part + base + 4);
        f[0]=p0.x; f[1]=p0.y; f[2]=p0.z; f[3]=p0.w;
        f[4]=p1.x; f[5]=p1.y; f[6]=p1.z; f[7]=p1.w;
    }
#pragma unroll
    for (int p = 1; p < NP; ++p) {
        const float4 p0 = *(const float4*)(part + (size_t)p * pzs + base);
        const float4 p1 = *(const float4*)(part + (size_t)p * pzs + base + 4);
        f[0]+=p0.x; f[1]+=p0.y; f[2]+=p0.z; f[3]+=p0.w;
        f[4]+=p1.x; f[5]+=p1.y; f[6]+=p1.z; f[7]+=p1.w;
    }
    {
        const float4 b0 = *(const float4*)(bias + l * 8);
        const float4 b1 = *(const float4*)(bias + l * 8 + 4);
        f[0]+=b0.x; f[1]+=b0.y; f[2]+=b0.z; f[3]+=b0.w;
        f[4]+=b1.x; f[5]+=b1.y; f[6]+=b1.z; f[7]+=b1.w;
    }
    if (RES) {
        const u16x8 r = *(const u16x8*)(res + base);
#pragma unroll
        for (int j = 0; j < 8; ++j) f[j] += bf2f(r[j]);
    }
    if (WRITEH) {
        u16x8 h;
#pragma unroll
        for (int j = 0; j < 8; ++j) h[j] = f2bf(f[j]);
        *(u16x8*)(outH + base) = h;
    }
    float s = 0.f, q = 0.f;
#pragma unroll
    for (int j = 0; j < 8; ++j) { s += f[j]; q += f[j] * f[j]; }
#pragma unroll
    for (int o = 32; o > 0; o >>= 1) { s += __shfl_xor(s, o); q += __shfl_xor(q, o); }
    const float mean = s * (1.f / 512.f);
    const float var = q * (1.f / 512.f) - mean * mean;
    const float rstd = rsqrtf(var + 1e-5f);
    u16x8 t;
#pragma unroll
    for (int j = 0; j < 8; ++j) {
        const int c = l * 8 + j;
        t[j] = f2bf((f[j] - mean) * rstd * g[c] + b[c]);
    }
    *(u16x8*)(outT + base) = t;
}

// f32 -> bf16 bulk convert, 8 elems/thread
__global__ __launch_bounds__(256) void cvt_f32_bf16(
    const float* __restrict__ in, u16* __restrict__ out, int n8)
{
    const int i = blockIdx.x * 256 + threadIdx.x;
    if (i >= n8) return;
    const float4* p = (const float4*)in + (size_t)i * 2;
    const float4 a = p[0], b = p[1];
    u16x8 v;
    v[0] = f2bf(a.x); v[1] = f2bf(a.y); v[2] = f2bf(a.z); v[3] = f2bf(a.w);
    v[4] = f2bf(b.x); v[5] = f2bf(b.y); v[6] = f2bf(b.z); v[7] = f2bf(b.w);
    *(u16x8*)(out + (size_t)i * 8) = v;
}

// per-head LN over 256 (rows are [8192,768], heads of 256), wave per (row,head)
__global__ __launch_bounds__(256) void lnh_kernel(
    const u16* __restrict__ in, const float* __restrict__ g,
    const float* __restrict__ b, u16* __restrict__ out)
{
    const int wid = threadIdx.x >> 6, l = threadIdx.x & 63;
    const int unit = blockIdx.x * 4 + wid;        // unit = h*8192 + row
    const int h = unit >> 13, row = unit & 8191;
    const size_t base = (size_t)row * 768 + h * 256 + l * 4;
    u16x4 v = *(const u16x4*)(in + base);
    float f[4], s = 0.f, q = 0.f;
#pragma unroll
    for (int j = 0; j < 4; ++j) { f[j] = bf2f(v[j]); s += f[j]; q += f[j] * f[j]; }
#pragma unroll
    for (int o = 32; o > 0; o >>= 1) { s += __shfl_xor(s, o); q += __shfl_xor(q, o); }
    const float mean = s * (1.f / 256.f);
    const float var = q * (1.f / 256.f) - mean * mean;
    const float rstd = rsqrtf(var + 1e-5f);
    u16x4 ov;
#pragma unroll
    for (int j = 0; j < 4; ++j) {
        const int c = h * 256 + l * 4 + j;
        ov[j] = f2bf((f[j] - mean) * rstd * g[c] + b[c]);
    }
    *(u16x4*)(out + base) = ov;
}

// out[N,K](bf16) = in[K,N](f32)^T, dims % 32 == 0, block = 256 (32x8)
__global__ __launch_bounds__(256) void transpose_kernel(
    const float* __restrict__ in, u16* __restrict__ out, int K, int N)
{
    __shared__ u16 t[32][33];
    const int n0 = blockIdx.x * 32, k0 = blockIdx.y * 32;
    const int tx = threadIdx.x & 31, ty = threadIdx.x >> 5;
#pragma unroll
    for (int i = 0; i < 32; i += 8)
        t[ty + i][tx] = f2bf(in[(size_t)(k0 + ty + i) * N + (n0 + tx)]);
    __syncthreads();
#pragma unroll
    for (int i = 0; i < 32; i += 8)
        out[(size_t)(n0 + ty + i) * K + (k0 + tx)] = t[tx][ty + i];
}

// Wh1t[768][512](bf16): Wh1t[h*256+k][d] = wh1[h][d][k]
__global__ void gather_wh1t(const float* __restrict__ wh1, u16* __restrict__ out)
{
    const int idx = blockIdx.x * 256 + threadIdx.x;
    if (idx >= 768 * 512) return;
    const int d = idx & 511, j = idx >> 9;
    const int h = j >> 8, kk = j & 255;
    out[idx] = f2bf(wh1[((size_t)(h * 512 + d)) * 256 + kk]);
}

// Wh2t[3][896][256](bf16): Wh2t[h][o][k] = wh2[h][k][o]
__global__ void gather_wh2t(const float* __restrict__ wh2, u16* __restrict__ out)
{
    const int idx = blockIdx.x * 256 + threadIdx.x;
    if (idx >= 3 * 896 * 256) return;
    const int kk = idx & 255, t = idx >> 8;
    const int h = t / 896, o = t - h * 896;
    out[idx] = f2bf(wh2[((size_t)(h * 256 + kk)) * 896 + o]);
}

// parallel bias prep: 8 blocks; block b covers i in [b*64, b*64+64).
__global__ __launch_bounds__(256) void prep_bias_kernel(
    const float* __restrict__ b_in, const float* __restrict__ pos,
    const float* __restrict__ bv_sa, const float* __restrict__ wo_sa,
    const float* __restrict__ bo_sa,
    const float* __restrict__ bv_ca, const float* __restrict__ wo_ca,
    const float* __restrict__ bo_ca,
    float* __restrict__ bias_in, float* __restrict__ b_comb)
{
    __shared__ float psa[4][64], pca[4][64];
    const int ii = threadIdx.x & 63, kg = threadIdx.x >> 6;
    const int i = blockIdx.x * 64 + ii;
    float sa = 0.f, ca = 0.f;
    for (int k = kg; k < 512; k += 4) {
        sa += bv_sa[k] * wo_sa[(size_t)k * 512 + i];
        ca += bv_ca[k] * wo_ca[(size_t)k * 512 + i];
    }
    psa[kg][ii] = sa; pca[kg][ii] = ca;
    __syncthreads();
    if (kg == 0) {
        bias_in[i] = b_in[i] + pos[i];
        b_comb[i] = psa[0][ii] + psa[1][ii] + psa[2][ii] + psa[3][ii]
                  + pca[0][ii] + pca[1][ii] + pca[2][ii] + pca[3][ii]
                  + bo_sa[i] + bo_ca[i];
    }
}

extern "C" void kernel_launch(void* const* d_in, const int* in_sizes, int n_in,
                              void* d_out, int out_size, void* d_ws, size_t ws_size,
                              hipStream_t stream)
{
    const float* x      = (const float*)d_in[0];
    const float* w_in   = (const float*)d_in[1];
    const float* b_in   = (const float*)d_in[2];
    const float* pos    = (const float*)d_in[3];
    const float* ln1_g  = (const float*)d_in[4];
    const float* ln1_b  = (const float*)d_in[5];
    const float* wv_sa  = (const float*)d_in[6];
    const float* bv_sa  = (const float*)d_in[7];
    const float* wo_sa  = (const float*)d_in[8];
    const float* bo_sa  = (const float*)d_in[9];
    const float* wv_ca  = (const float*)d_in[12];
    const float* bv_ca  = (const float*)d_in[13];
    const float* wo_ca  = (const float*)d_in[14];
    const float* bo_ca  = (const float*)d_in[15];
    const float* ln3_g  = (const float*)d_in[16];
    const float* ln3_b  = (const float*)d_in[17];
    const float* w_ff1  = (const float*)d_in[18];
    const float* b_ff1  = (const float*)d_in[19];
    const float* w_ff2  = (const float*)d_in[20];
    const float* b_ff2  = (const float*)d_in[21];
    const float* lnoutg = (const float*)d_in[22];
    const float* lnoutb = (const float*)d_in[23];
    const float* wh1    = (const float*)d_in[24];
    const float* bh1    = (const float*)d_in[25];
    const float* lnh_g  = (const float*)d_in[26];
    const float* lnh_b  = (const float*)d_in[27];
    const float* wh2    = (const float*)d_in[28];
    const float* bh2    = (const float*)d_in[29];
    float* out = (float*)d_out;
    const int KBIG = 0x7fffffff;

    // ---- workspace layout (~70 MB, rewritten fully every call) ----
    char* wsp = (char*)d_ws;
    size_t off = 0;
    auto ALLOC = [&](size_t n) { char* r = wsp + off; off = (off + n + 255) & ~(size_t)255; return r; };
    u16* w_inT  = (u16*)ALLOC(512UL * 4096 * 2);
    u16* wff1t  = (u16*)ALLOC(2048UL * 512 * 2);
    u16* wff2t  = (u16*)ALLOC(512UL * 2048 * 2);
    u16* woT2   = (u16*)ALLOC(2UL * 512 * 512 * 2);  // [0]=woTca, [1]=woTsa
    u16* wv2b   = (u16*)ALLOC(2UL * 512 * 512 * 2);  // [0]=wv_ca, [1]=wv_sa
    u16* Wct    = (u16*)ALLOC(512UL * 1024 * 2);     // [n][k] k<512: ca, k>=512: sa
    u16* Wh1t   = (u16*)ALLOC(768UL * 512 * 2);
    u16* Wh2t   = (u16*)ALLOC(3UL * 896 * 256 * 2);
    float* bias_in = (float*)ALLOC(512 * 4);
    float* b_comb  = (float*)ALLOC(512 * 4);
    u16* h0   = (u16*)ALLOC(8192UL * 512 * 2);   // h0
    u16* T    = (u16*)ALLOC(8192UL * 512 * 2);   // ln1 / ln3 / lnout output
    u16* hbuf = (u16*)ALLOC(8192UL * 512 * 2);   // h2
    u16* G    = (u16*)ALLOC(8192UL * 2048 * 2);  // FF intermediate; Z/Z2 alias
    u16* Z  = G;
    u16* Z2 = (u16*)((char*)G + 8192UL * 768 * 2);
    // ALL split-K partials live in d_out (88 MB, dead until final heads GEMM)
    float* partO = out;
    const long PZS = 8192L * 512;

    // ---- weight prep ----
    cvt_f32_bf16<<<128, 256, 0, stream>>>(wv_ca, wv2b, 512 * 512 / 8);
    cvt_f32_bf16<<<128, 256, 0, stream>>>(wv_sa, wv2b + 512 * 512, 512 * 512 / 8);
    prep_bias_kernel<<<8, 256, 0, stream>>>(b_in, pos, bv_sa, wo_sa, bo_sa,
        bv_ca, wo_ca, bo_ca, bias_in, b_comb);
    transpose_kernel<<<dim3(16, 128), 256, 0, stream>>>(w_in, w_inT, 4096, 512);
    transpose_kernel<<<dim3(64, 16), 256, 0, stream>>>(w_ff1, wff1t, 512, 2048);
    transpose_kernel<<<dim3(16, 64), 256, 0, stream>>>(w_ff2, wff2t, 2048, 512);
    transpose_kernel<<<dim3(16, 16), 256, 0, stream>>>(wo_ca, woT2, 512, 512);
    transpose_kernel<<<dim3(16, 16), 256, 0, stream>>>(wo_sa, woT2 + 512 * 512, 512, 512);
    gather_wh1t<<<1536, 256, 0, stream>>>(wh1, Wh1t);
    gather_wh2t<<<2688, 256, 0, stream>>>(wh2, Wh2t);
    // Wct (z-batched): z=0 -> ca half (k<512), z=1 -> sa half (k>=512)
    gemm64<false, false, false, false, false><<<dim3(8, 4, 2), 256, 0, stream>>>(
        woT2, nullptr, KBIG, wv2b, nullptr, nullptr, 0, Wct,
        512, 512, 512, 1024, 512 * 512, 512 * 512, 0, 512, 0);

    // ---- main pipeline ----
    // GEMM1 split-K x3 -> partials in d_out; fused reduce+bias -> h0, T=ln1
    gemm64<false, false, true, false, true><<<dim3(128, 4, 3), 256, 0, stream>>>(
        x, nullptr, KBIG, w_inT, nullptr, nullptr, 0, partO,
        4096, 4096, 4096, 512, 0, 0, 0, PZS, 1376);
    reduceLN512<3, false, true><<<2048, 256, 0, stream>>>(
        partO, PZS, bias_in, nullptr, ln1_g, ln1_b, h0, T);
    // attention split-K x2: [h0 | T] @ Wct -> partials; fused reduce +b_comb
    // +h0 residual -> hbuf=h2, T=ln3
    gemm64<false, false, false, false, true><<<dim3(128, 4, 2), 256, 0, stream>>>(
        h0, T, 512, Wct, nullptr, nullptr, 0, partO,
        1024, 512, 1024, 512, 0, 0, 0, PZS, 512);
    reduceLN512<2, true, true><<<2048, 256, 0, stream>>>(
        partO, PZS, b_comb, h0, ln3_g, ln3_b, hbuf, T);
    // G = gelu(T @ w_ff1 + b_ff1)   [8192, 2048]
    gemm64<true, false, false, false, false><<<dim3(128, 16), 256, 0, stream>>>(
        T, nullptr, KBIG, wff1t, b_ff1, nullptr, 0, G,
        512, 512, 512, 2048, 0, 0, 0, 0, 0);
    // FF2 split-K x2 -> partials; fused reduce +b_ff2 +h2 residual -> T=lnout
    // (h3 itself is not needed downstream)
    gemm64<false, false, false, false, true><<<dim3(128, 4, 2), 256, 0, stream>>>(
        G, nullptr, KBIG, wff2t, nullptr, nullptr, 0, partO,
        2048, 2048, 2048, 512, 0, 0, 0, PZS, 1024);
    reduceLN512<2, true, false><<<2048, 256, 0, stream>>>(
        partO, PZS, b_ff2, hbuf, lnoutg, lnoutb, nullptr, T);
    // Z = gelu(T @ Wh1 + bh1)   [8192, 768]
    gemm64<true, false, false, false, false><<<dim3(128, 6), 256, 0, stream>>>(
        T, nullptr, KBIG, Wh1t, bh1, nullptr, 0, Z,
        512, 512, 512, 768, 0, 0, 0, 0, 0);
    // Z2 = per-head LN(Z)
    lnh_kernel<<<6144, 256, 0, stream>>>(Z, lnh_g, lnh_b, Z2);
    // out[:, z*896:(z+1)*896] = Z2[:, z*256:+256] @ wh2[z] + bh2[z]
    // (f32, z-batched; overwrites ALL partial scratch in d_out)
    gemm64<false, false, false, true, false><<<dim3(128, 7, 3), 256, 0, stream>>>(
        Z2, nullptr, KBIG, Wh2t, bh2, nullptr, 0, out,
        256, 768, 256, 2688, 256, 896 * 256, 896, 896, 0);
}

// Round 17
// 372.996 us; speedup vs baseline: 1.1404x; 1.0349x over previous
//
#include <hip/hip_runtime.h>
#include <math.h>

// ---------------------------------------------------------------------------
// RFSQDraftModelWithProjection — f32 in / f32 out, bf16 MFMA compute.
// r17: BK=64 (16 MFMA / K-step, half the barrier pairs) + both-sides XOR
// LDS swizzle (rule 21: linear gload_lds dest + pre-swizzled global source +
// swizzled ds_read) -> 16-way bank conflict becomes 2-way (free).
// Everything else = r16 (fused reduceLN, fast GELU, split-K in d_out).
// ---------------------------------------------------------------------------

typedef unsigned short u16;
typedef __attribute__((ext_vector_type(8))) short bf16x8;
typedef __attribute__((ext_vector_type(4))) float f32x4;
typedef __attribute__((ext_vector_type(8))) unsigned short u16x8;
typedef __attribute__((ext_vector_type(4))) unsigned short u16x4;

__device__ __forceinline__ float bf2f(u16 u){
    union { unsigned int i; float f; } x; x.i = ((unsigned int)u) << 16; return x.f;
}
__device__ __forceinline__ u16 f2bf(float f){
    union { float f; unsigned int i; } x; x.f = f;
    unsigned int r = x.i + 0x7fffu + ((x.i >> 16) & 1u);
    return (u16)(r >> 16);
}
// tanh-form GELU via 1 HW exp; |diff vs erf-GELU| <~3e-3.
__device__ __forceinline__ float gelu_fast(float v){
    const float u = 1.5957691216f * v * (1.0f + 0.044715f * v * v);
    const float e = __expf(u);
    return v * (1.0f - 1.0f / (e + 1.0f));
}
#define GLOAD16(src, dst) __builtin_amdgcn_global_load_lds( \
    (const __attribute__((address_space(1))) void*)(src),   \
    (__attribute__((address_space(3))) void*)(dst), 16, 0, 0)
#define SCHED0 __builtin_amdgcn_sched_barrier(0)

// ---------------------------------------------------------------------------
// gemm64: C[M,N] = A[M,K] @ B[K,N] (+bias +res, opt GELU). 64x128 tile,
// BK=64, 4 waves, 16 MFMA/step, counted-vmcnt double buffer.
// LDS layout [rows][8 chunks of 16B]; position (row, c) holds global chunk
// (row, c ^ (row&7)); ds_read XORs the chunk index the same way.
// blockIdx.x = m-tile (gridDim.x % 8 == 0 -> XCD A-panel reuse),
// blockIdx.y = n-tile.  AF32: f32 A, depth-2 register prefetch.
// A2/ksplit: concat A source at k=ksplit (64 | ksplit).  PART: z = k-chunk
// (kch % 64 == 0), f32 partials at Cout + z*czs.  Else z = batch via strides.
// ---------------------------------------------------------------------------
template<bool GELU, bool RES, bool AF32, bool OUTF32, bool PART>
__global__ __launch_bounds__(256) void gemm64(
    const void* __restrict__ A, const void* __restrict__ A2, int ksplit,
    const u16* __restrict__ Bt, const float* __restrict__ bias,
    const u16* __restrict__ res, int ldr,
    void* __restrict__ Cout, int K, int lda, int ldb, int ldc,
    long azs, long bzs, int biaszs, long czs, int kch)
{
    __shared__ __align__(16) u16 As[2][64 * 64];
    __shared__ __align__(16) u16 Bs[2][128 * 64];
    const int tid = threadIdx.x;
    const int w = tid >> 6, l = tid & 63;
    const int wr = w >> 1, wc = w & 1;
    const int m0 = blockIdx.x * 64, n0 = blockIdx.y * 128;
    const int z = blockIdx.z;
    int kbeg = 0, kend = K;
    if (PART) { kbeg = z * kch; kend = min(kbeg + kch, K); }
    const u16* A16 = (const u16*)A + (PART ? 0 : (size_t)z * azs);
    const float* Af = (const float*)A;
    const u16* BtZ = Bt + (PART ? 0 : (size_t)z * bzs);
    const int swc = (l & 7) ^ (l >> 3);   // pre-swizzled source chunk

    f32x4 acc[2][4];
#pragma unroll
    for (int i = 0; i < 2; ++i)
#pragma unroll
        for (int j = 0; j < 4; ++j) acc[i][j] = (f32x4){0.f, 0.f, 0.f, 0.f};

    // stage B tile (128 rows x 64 cols bf16): 4 gload_lds per wave,
    // 8 rows per instruction, source chunk XOR-swizzled.
    auto stageB = [&](int buf, int k0) {
#pragma unroll
        for (int j = 0; j < 4; ++j) {
            const int rb = w * 32 + j * 8;
            const u16* gb = BtZ + (size_t)(n0 + rb + (l >> 3)) * ldb + k0 + swc * 8;
            GLOAD16(gb, &Bs[buf][rb * 64]);
        }
    };
    auto stageA16 = [&](int buf, int k0) {
        const u16* base = (k0 >= ksplit) ? ((const u16*)A2 + (k0 - ksplit)) : (A16 + k0);
#pragma unroll
        for (int j = 0; j < 2; ++j) {
            const int rb = w * 16 + j * 8;
            const u16* ga = base + (size_t)(m0 + rb + (l >> 3)) * lda + swc * 8;
            GLOAD16(ga, &As[buf][rb * 64]);
        }
    };
    // AF32: thread covers row tid>>2, 16 f32 at col (tid&3)*16 (4 float4)
    auto loadA = [&](int k0, float4& p0, float4& p1, float4& p2, float4& p3) {
        const float* g = Af + (size_t)(m0 + (tid >> 2)) * lda + k0 + (tid & 3) * 16;
        p0 = *(const float4*)g;       p1 = *(const float4*)(g + 4);
        p2 = *(const float4*)(g + 8); p3 = *(const float4*)(g + 12);
    };
    auto writeA = [&](const float4& p0, const float4& p1, const float4& p2,
                      const float4& p3, int buf) {
        const int row = tid >> 2, c0 = (tid & 3) * 2;
        u16x8 v0, v1;
        v0[0] = f2bf(p0.x); v0[1] = f2bf(p0.y); v0[2] = f2bf(p0.z); v0[3] = f2bf(p0.w);
        v0[4] = f2bf(p1.x); v0[5] = f2bf(p1.y); v0[6] = f2bf(p1.z); v0[7] = f2bf(p1.w);
        v1[0] = f2bf(p2.x); v1[1] = f2bf(p2.y); v1[2] = f2bf(p2.z); v1[3] = f2bf(p2.w);
        v1[4] = f2bf(p3.x); v1[5] = f2bf(p3.y); v1[6] = f2bf(p3.z); v1[7] = f2bf(p3.w);
        *(u16x8*)&As[buf][row * 64 + ((c0)     ^ (row & 7)) * 8] = v0;
        *(u16x8*)&As[buf][row * 64 + ((c0 + 1) ^ (row & 7)) * 8] = v1;
    };
    int cur = 0;
    auto compute = [&]() {
#pragma unroll
        for (int kk = 0; kk < 2; ++kk) {
            const int kcb = kk * 4 + (l >> 4);
            bf16x8 a[2], b[4];
#pragma unroll
            for (int i = 0; i < 2; ++i) {
                const int row = wr * 32 + i * 16 + (l & 15);
                a[i] = *(const bf16x8*)&As[cur][row * 64 + (kcb ^ (l & 7)) * 8];
            }
#pragma unroll
            for (int j = 0; j < 4; ++j) {
                const int row = wc * 64 + j * 16 + (l & 15);
                b[j] = *(const bf16x8*)&Bs[cur][row * 64 + (kcb ^ (l & 7)) * 8];
            }
#pragma unroll
            for (int i = 0; i < 2; ++i)
#pragma unroll
                for (int j = 0; j < 4; ++j)
                    acc[i][j] = __builtin_amdgcn_mfma_f32_16x16x32_bf16(a[i], b[j], acc[i][j], 0, 0, 0);
        }
    };

    const int nt = (kend - kbeg) >> 6;
    if (AF32) {
        float4 a0, a1, a2, a3, b0, b1, b2, b3;
        loadA(kbeg, a0, a1, a2, a3);
        stageB(0, kbeg);
        if (nt > 1) {
            loadA(kbeg + 64, b0, b1, b2, b3);
            asm volatile("s_waitcnt vmcnt(4)" ::: "memory");
        } else {
            asm volatile("s_waitcnt vmcnt(0)" ::: "memory");
        }
        writeA(a0, a1, a2, a3, 0);
        asm volatile("s_waitcnt lgkmcnt(0)" ::: "memory");
        auto stepA = [&](int t, float4& w0, float4& w1, float4& w2, float4& w3,
                         float4& l0, float4& l1, float4& l2, float4& l3) {
            const bool ldA = (t + 2) < nt;
            const bool stB = (t + 1) < nt;
            if (ldA) loadA(kbeg + ((t + 2) << 6), l0, l1, l2, l3);
            if (stB) stageB(cur ^ 1, kbeg + ((t + 1) << 6));
            if (ldA)      asm volatile("s_waitcnt vmcnt(8)" ::: "memory");
            else if (stB) asm volatile("s_waitcnt vmcnt(4)" ::: "memory");
            else          asm volatile("s_waitcnt vmcnt(0)" ::: "memory");
            SCHED0;
            __builtin_amdgcn_s_barrier();
            SCHED0;
            compute();
            if (stB) writeA(w0, w1, w2, w3, cur ^ 1);
            asm volatile("s_waitcnt lgkmcnt(0)" ::: "memory");
            SCHED0;
            __builtin_amdgcn_s_barrier();
            SCHED0;
            cur ^= 1;
        };
        int t = 0;
        while (t + 2 <= nt) {
            stepA(t,     b0, b1, b2, b3, a0, a1, a2, a3);
            stepA(t + 1, a0, a1, a2, a3, b0, b1, b2, b3);
            t += 2;
        }
        if (t < nt) stepA(t, b0, b1, b2, b3, a0, a1, a2, a3);
    } else {
        stageA16(0, kbeg);
        stageB(0, kbeg);
        for (int t = 0; t < nt; ++t) {
            const bool more = (t + 1) < nt;
            if (more) {
                const int kn = kbeg + ((t + 1) << 6);
                stageA16(cur ^ 1, kn);
                stageB(cur ^ 1, kn);
            }
            if (more) asm volatile("s_waitcnt vmcnt(6)" ::: "memory");
            else      asm volatile("s_waitcnt vmcnt(0)" ::: "memory");
            SCHED0;
            __builtin_amdgcn_s_barrier();
            SCHED0;
            compute();
            asm volatile("" ::: "memory");
            SCHED0;
            __builtin_amdgcn_s_barrier();
            SCHED0;
            cur ^= 1;
        }
    }

    // epilogue: C/D layout col = l&15, row = (l>>4)*4 + r  [m89/m91]
    float* cF = (float*)Cout + (size_t)z * czs;
    u16*   cH = (u16*)Cout + (size_t)z * czs;
    const float* biasZ = (!PART && bias) ? bias + (size_t)z * biaszs : nullptr;
#pragma unroll
    for (int i = 0; i < 2; ++i) {
#pragma unroll
        for (int j = 0; j < 4; ++j) {
            const int col = n0 + wc * 64 + j * 16 + (l & 15);
            const int rowb = m0 + wr * 32 + i * 16 + (l >> 4) * 4;
#pragma unroll
            for (int r = 0; r < 4; ++r) {
                const int row = rowb + r;
                float v = acc[i][j][r];
                if (PART) {
                    cF[(size_t)row * ldc + col] = v;
                } else {
                    if (biasZ) v += biasZ[col];
                    if (RES) v += bf2f(res[(size_t)row * ldr + col]);
                    if (GELU) v = gelu_fast(v);
                    if (OUTF32) cF[(size_t)row * ldc + col] = v;
                    else        cH[(size_t)row * ldc + col] = f2bf(v);
                }
            }
        }
    }
}

// ---------------------------------------------------------------------------
// reduceLN512: fused split-K reduce + bias (+res) -> optional bf16 H-write,
// then row LayerNorm (512 cols) -> bf16 T-write. One wave per row.
// ---------------------------------------------------------------------------
template<int NP, bool RES, bool WRITEH>
__global__ __launch_bounds__(256) void reduceLN512(
    const float* __restrict__ part, long pzs, const float* __restrict__ bias,
    const u16* __restrict__ res, const float* __restrict__ g,
    const float* __restrict__ b, u16* __restrict__ outH, u16* __restrict__ outT)
{
    const int wid = threadIdx.x >> 6, l = threadIdx.x & 63;
    const size_t row = (size_t)blockIdx.x * 4 + wid;
    const size_t base = row * 512 + l * 8;
    float f[8];
    {
        const float4 p0 = *(const float4*)(part + base);
        const float4 p1 = *(const float4*)(part + base + 4);
        f[0]=p0.x; f[1]=p0.y; f[2]=p0.z; f[3]=p0.w;
        f[4]=p1.x; f[5]=p1.y; f[6]=p1.z; f[7]=p1.w;
    }
#pragma unroll
    for (int p = 1; p < NP; ++p) {
        const float4 p0 = *(const float4*)(part + (size_t)p * pzs + base);
        const float4 p1 = *(const float4*)(part + (size_t)p * pzs + base + 4);
        f[0]+=p0.x; f[1]+=p0.y; f[2]+=p0.z; f[3]+=p0.w;
        f[4]+=p1.x; f[5]+=p1.y; f[6]+=p1.z; f[7]+=p1.w;
    }
    {
        const float4 b0 = *(const float4*)(bias + l * 8);
        const float4 b1 = *(const float4*)(bias + l * 8 + 4);
        f[0]+=b0.x; f[1]+=b0.y; f[2]+=b0.z; f[3]+=b0.w;
        f[4]+=b1.x; f[5]+=b1.y; f[6]+=b1.z; f[7]+=b1.w;
    }
    if (RES) {
        const u16x8 r = *(const u16x8*)(res + base);
#pragma unroll
        for (int j = 0; j < 8; ++j) f[j] += bf2f(r[j]);
    }
    if (WRITEH) {
        u16x8 h;
#pragma unroll
        for (int j = 0; j < 8; ++j) h[j] = f2bf(f[j]);
        *(u16x8*)(outH + base) = h;
    }
    float s = 0.f, q = 0.f;
#pragma unroll
    for (int j = 0; j < 8; ++j) { s += f[j]; q += f[j] * f[j]; }
#pragma unroll
    for (int o = 32; o > 0; o >>= 1) { s += __shfl_xor(s, o); q += __shfl_xor(q, o); }
    const float mean = s * (1.f / 512.f);
    const float var = q * (1.f / 512.f) - mean * mean;
    const float rstd = rsqrtf(var + 1e-5f);
    u16x8 t;
#pragma unroll
    for (int j = 0; j < 8; ++j) {
        const int c = l * 8 + j;
        t[j] = f2bf((f[j] - mean) * rstd * g[c] + b[c]);
    }
    *(u16x8*)(outT + base) = t;
}

// f32 -> bf16 bulk convert, 8 elems/thread
__global__ __launch_bounds__(256) void cvt_f32_bf16(
    const float* __restrict__ in, u16* __restrict__ out, int n8)
{
    const int i = blockIdx.x * 256 + threadIdx.x;
    if (i >= n8) return;
    const float4* p = (const float4*)in + (size_t)i * 2;
    const float4 a = p[0], b = p[1];
    u16x8 v;
    v[0] = f2bf(a.x); v[1] = f2bf(a.y); v[2] = f2bf(a.z); v[3] = f2bf(a.w);
    v[4] = f2bf(b.x); v[5] = f2bf(b.y); v[6] = f2bf(b.z); v[7] = f2bf(b.w);
    *(u16x8*)(out + (size_t)i * 8) = v;
}

// per-head LN over 256 (rows are [8192,768], heads of 256), wave per (row,head)
__global__ __launch_bounds__(256) void lnh_kernel(
    const u16* __restrict__ in, const float* __restrict__ g,
    const float* __restrict__ b, u16* __restrict__ out)
{
    const int wid = threadIdx.x >> 6, l = threadIdx.x & 63;
    const int unit = blockIdx.x * 4 + wid;        // unit = h*8192 + row
    const int h = unit >> 13, row = unit & 8191;
    const size_t base = (size_t)row * 768 + h * 256 + l * 4;
    u16x4 v = *(const u16x4*)(in + base);
    float f[4], s = 0.f, q = 0.f;
#pragma unroll
    for (int j = 0; j < 4; ++j) { f[j] = bf2f(v[j]); s += f[j]; q += f[j] * f[j]; }
#pragma unroll
    for (int o = 32; o > 0; o >>= 1) { s += __shfl_xor(s, o); q += __shfl_xor(q, o); }
    const float mean = s * (1.f / 256.f);
    const float var = q * (1.f / 256.f) - mean * mean;
    const float rstd = rsqrtf(var + 1e-5f);
    u16x4 ov;
#pragma unroll
    for (int j = 0; j < 4; ++j) {
        const int c = h * 256 + l * 4 + j;
        ov[j] = f2bf((f[j] - mean) * rstd * g[c] + b[c]);
    }
    *(u16x4*)(out + base) = ov;
}

// out[N,K](bf16) = in[K,N](f32)^T, dims % 32 == 0, block = 256 (32x8)
__global__ __launch_bounds__(256) void transpose_kernel(
    const float* __restrict__ in, u16* __restrict__ out, int K, int N)
{
    __shared__ u16 t[32][33];
    const int n0 = blockIdx.x * 32, k0 = blockIdx.y * 32;
    const int tx = threadIdx.x & 31, ty = threadIdx.x >> 5;
#pragma unroll
    for (int i = 0; i < 32; i += 8)
        t[ty + i][tx] = f2bf(in[(size_t)(k0 + ty + i) * N + (n0 + tx)]);
    __syncthreads();
#pragma unroll
    for (int i = 0; i < 32; i += 8)
        out[(size_t)(n0 + ty + i) * K + (k0 + tx)] = t[tx][ty + i];
}

// Wh1t[768][512](bf16): Wh1t[h*256+k][d] = wh1[h][d][k]
__global__ void gather_wh1t(const float* __restrict__ wh1, u16* __restrict__ out)
{
    const int idx = blockIdx.x * 256 + threadIdx.x;
    if (idx >= 768 * 512) return;
    const int d = idx & 511, j = idx >> 9;
    const int h = j >> 8, kk = j & 255;
    out[idx] = f2bf(wh1[((size_t)(h * 512 + d)) * 256 + kk]);
}

// Wh2t[3][896][256](bf16): Wh2t[h][o][k] = wh2[h][k][o]
__global__ void gather_wh2t(const float* __restrict__ wh2, u16* __restrict__ out)
{
    const int idx = blockIdx.x * 256 + threadIdx.x;
    if (idx >= 3 * 896 * 256) return;
    const int kk = idx & 255, t = idx >> 8;
    const int h = t / 896, o = t - h * 896;
    out[idx] = f2bf(wh2[((size_t)(h * 256 + kk)) * 896 + o]);
}

// parallel bias prep: 8 blocks; block b covers i in [b*64, b*64+64).
__global__ __launch_bounds__(256) void prep_bias_kernel(
    const float* __restrict__ b_in, const float* __restrict__ pos,
    const float* __restrict__ bv_sa, const float* __restrict__ wo_sa,
    const float* __restrict__ bo_sa,
    const float* __restrict__ bv_ca, const float* __restrict__ wo_ca,
    const float* __restrict__ bo_ca,
    float* __restrict__ bias_in, float* __restrict__ b_comb)
{
    __shared__ float psa[4][64], pca[4][64];
    const int ii = threadIdx.x & 63, kg = threadIdx.x >> 6;
    const int i = blockIdx.x * 64 + ii;
    float sa = 0.f, ca = 0.f;
    for (int k = kg; k < 512; k += 4) {
        sa += bv_sa[k] * wo_sa[(size_t)k * 512 + i];
        ca += bv_ca[k] * wo_ca[(size_t)k * 512 + i];
    }
    psa[kg][ii] = sa; pca[kg][ii] = ca;
    __syncthreads();
    if (kg == 0) {
        bias_in[i] = b_in[i] + pos[i];
        b_comb[i] = psa[0][ii] + psa[1][ii] + psa[2][ii] + psa[3][ii]
                  + pca[0][ii] + pca[1][ii] + pca[2][ii] + pca[3][ii]
                  + bo_sa[i] + bo_ca[i];
    }
}

extern "C" void kernel_launch(void* const* d_in, const int* in_sizes, int n_in,
                              void* d_out, int out_size, void* d_ws, size_t ws_size,
                              hipStream_t stream)
{
    const float* x      = (const float*)d_in[0];
    const float* w_in   = (const float*)d_in[1];
    const float* b_in   = (const float*)d_in[2];
    const float* pos    = (const float*)d_in[3];
    const float* ln1_g  = (const float*)d_in[4];
    const float* ln1_b  = (const float*)d_in[5];
    const float* wv_sa  = (const float*)d_in[6];
    const float* bv_sa  = (const float*)d_in[7];
    const float* wo_sa  = (const float*)d_in[8];
    const float* bo_sa  = (const float*)d_in[9];
    const float* wv_ca  = (const float*)d_in[12];
    const float* bv_ca  = (const float*)d_in[13];
    const float* wo_ca  = (const float*)d_in[14];
    const float* bo_ca  = (const float*)d_in[15];
    const float* ln3_g  = (const float*)d_in[16];
    const float* ln3_b  = (const float*)d_in[17];
    const float* w_ff1  = (const float*)d_in[18];
    const float* b_ff1  = (const float*)d_in[19];
    const float* w_ff2  = (const float*)d_in[20];
    const float* b_ff2  = (const float*)d_in[21];
    const float* lnoutg = (const float*)d_in[22];
    const float* lnoutb = (const float*)d_in[23];
    const float* wh1    = (const float*)d_in[24];
    const float* bh1    = (const float*)d_in[25];
    const float* lnh_g  = (const float*)d_in[26];
    const float* lnh_b  = (const float*)d_in[27];
    const float* wh2    = (const float*)d_in[28];
    const float* bh2    = (const float*)d_in[29];
    float* out = (float*)d_out;
    const int KBIG = 0x7fffffff;

    // ---- workspace layout (~70 MB, rewritten fully every call) ----
    char* wsp = (char*)d_ws;
    size_t off = 0;
    auto ALLOC = [&](size_t n) { char* r = wsp + off; off = (off + n + 255) & ~(size_t)255; return r; };
    u16* w_inT  = (u16*)ALLOC(512UL * 4096 * 2);
    u16* wff1t  = (u16*)ALLOC(2048UL * 512 * 2);
    u16* wff2t  = (u16*)ALLOC(512UL * 2048 * 2);
    u16* woT2   = (u16*)ALLOC(2UL * 512 * 512 * 2);  // [0]=woTca, [1]=woTsa
    u16* wv2b   = (u16*)ALLOC(2UL * 512 * 512 * 2);  // [0]=wv_ca, [1]=wv_sa
    u16* Wct    = (u16*)ALLOC(512UL * 1024 * 2);     // [n][k] k<512: ca, k>=512: sa
    u16* Wh1t   = (u16*)ALLOC(768UL * 512 * 2);
    u16* Wh2t   = (u16*)ALLOC(3UL * 896 * 256 * 2);
    float* bias_in = (float*)ALLOC(512 * 4);
    float* b_comb  = (float*)ALLOC(512 * 4);
    u16* h0   = (u16*)ALLOC(8192UL * 512 * 2);   // h0
    u16* T    = (u16*)ALLOC(8192UL * 512 * 2);   // ln1 / ln3 / lnout output
    u16* hbuf = (u16*)ALLOC(8192UL * 512 * 2);   // h2
    u16* G    = (u16*)ALLOC(8192UL * 2048 * 2);  // FF intermediate; Z/Z2 alias
    u16* Z  = G;
    u16* Z2 = (u16*)((char*)G + 8192UL * 768 * 2);
    // ALL split-K partials live in d_out (88 MB, dead until final heads GEMM)
    float* partO = out;
    const long PZS = 8192L * 512;

    // ---- weight prep ----
    cvt_f32_bf16<<<128, 256, 0, stream>>>(wv_ca, wv2b, 512 * 512 / 8);
    cvt_f32_bf16<<<128, 256, 0, stream>>>(wv_sa, wv2b + 512 * 512, 512 * 512 / 8);
    prep_bias_kernel<<<8, 256, 0, stream>>>(b_in, pos, bv_sa, wo_sa, bo_sa,
        bv_ca, wo_ca, bo_ca, bias_in, b_comb);
    transpose_kernel<<<dim3(16, 128), 256, 0, stream>>>(w_in, w_inT, 4096, 512);
    transpose_kernel<<<dim3(64, 16), 256, 0, stream>>>(w_ff1, wff1t, 512, 2048);
    transpose_kernel<<<dim3(16, 64), 256, 0, stream>>>(w_ff2, wff2t, 2048, 512);
    transpose_kernel<<<dim3(16, 16), 256, 0, stream>>>(wo_ca, woT2, 512, 512);
    transpose_kernel<<<dim3(16, 16), 256, 0, stream>>>(wo_sa, woT2 + 512 * 512, 512, 512);
    gather_wh1t<<<1536, 256, 0, stream>>>(wh1, Wh1t);
    gather_wh2t<<<2688, 256, 0, stream>>>(wh2, Wh2t);
    // Wct (z-batched): z=0 -> ca half (k<512), z=1 -> sa half (k>=512)
    gemm64<false, false, false, false, false><<<dim3(8, 4, 2), 256, 0, stream>>>(
        woT2, nullptr, KBIG, wv2b, nullptr, nullptr, 0, Wct,
        512, 512, 512, 1024, 512 * 512, 512 * 512, 0, 512, 0);

    // ---- main pipeline ----
    // GEMM1 split-K x3 (kch=1408: 1408/1408/1280) -> partials in d_out;
    // fused reduce+bias -> h0, T=ln1
    gemm64<false, false, true, false, true><<<dim3(128, 4, 3), 256, 0, stream>>>(
        x, nullptr, KBIG, w_inT, nullptr, nullptr, 0, partO,
        4096, 4096, 4096, 512, 0, 0, 0, PZS, 1408);
    reduceLN512<3, false, true><<<2048, 256, 0, stream>>>(
        partO, PZS, bias_in, nullptr, ln1_g, ln1_b, h0, T);
    // attention split-K x2: [h0 | T] @ Wct -> partials; fused reduce +b_comb
    // +h0 residual -> hbuf=h2, T=ln3
    gemm64<false, false, false, false, true><<<dim3(128, 4, 2), 256, 0, stream>>>(
        h0, T, 512, Wct, nullptr, nullptr, 0, partO,
        1024, 512, 1024, 512, 0, 0, 0, PZS, 512);
    reduceLN512<2, true, true><<<2048, 256, 0, stream>>>(
        partO, PZS, b_comb, h0, ln3_g, ln3_b, hbuf, T);
    // G = gelu(T @ w_ff1 + b_ff1)   [8192, 2048]
    gemm64<true, false, false, false, false><<<dim3(128, 16), 256, 0, stream>>>(
        T, nullptr, KBIG, wff1t, b_ff1, nullptr, 0, G,
        512, 512, 512, 2048, 0, 0, 0, 0, 0);
    // FF2 split-K x2 -> partials; fused reduce +b_ff2 +h2 residual -> T=lnout
    gemm64<false, false, false, false, true><<<dim3(128, 4, 2), 256, 0, stream>>>(
        G, nullptr, KBIG, wff2t, nullptr, nullptr, 0, partO,
        2048, 2048, 2048, 512, 0, 0, 0, PZS, 1024);
    reduceLN512<2, true, false><<<2048, 256, 0, stream>>>(
        partO, PZS, b_ff2, hbuf, lnoutg, lnoutb, nullptr, T);
    // Z = gelu(T @ Wh1 + bh1)   [8192, 768]
    gemm64<true, false, false, false, false><<<dim3(128, 6), 256, 0, stream>>>(
        T, nullptr, KBIG, Wh1t, bh1, nullptr, 0, Z,
        512, 512, 512, 768, 0, 0, 0, 0, 0);
    // Z2 = per-head LN(Z)
    lnh_kernel<<<6144, 256, 0, stream>>>(Z, lnh_g, lnh_b, Z2);
    // out[:, z*896:(z+1)*896] = Z2[:, z*256:+256] @ wh2[z] + bh2[z]
    // (f32, z-batched; overwrites ALL partial scratch in d_out)
    gemm64<false, false, false, true, false><<<dim3(128, 7, 3), 256, 0, stream>>>(
        Z2, nullptr, KBIG, Wh2t, bh2, nullptr, 0, out,
        256, 768, 256, 2688, 256, 896 * 256, 896, 896, 0);
}

// Round 18
// 338.776 us; speedup vs baseline: 1.2556x; 1.1010x over previous
//
#include <hip/hip_runtime.h>
#include <math.h>

// ---------------------------------------------------------------------------
// RFSQDraftModelWithProjection — f32 in / f32 out, bf16 MFMA compute.
// r18: r17 GEMM config (BK=64, both-sides XOR swizzle => 0 bank conflicts,
// counted vmcnt, split-K in d_out, fused reduceLN, fast GELU) + ALL weight
// prep consolidated into ONE mega-kernel (9096 blocks, block-range dispatch)
// — dispatch count 19 -> 12.
// ---------------------------------------------------------------------------

typedef unsigned short u16;
typedef __attribute__((ext_vector_type(8))) short bf16x8;
typedef __attribute__((ext_vector_type(4))) float f32x4;
typedef __attribute__((ext_vector_type(8))) unsigned short u16x8;
typedef __attribute__((ext_vector_type(4))) unsigned short u16x4;

__device__ __forceinline__ float bf2f(u16 u){
    union { unsigned int i; float f; } x; x.i = ((unsigned int)u) << 16; return x.f;
}
__device__ __forceinline__ u16 f2bf(float f){
    union { float f; unsigned int i; } x; x.f = f;
    unsigned int r = x.i + 0x7fffu + ((x.i >> 16) & 1u);
    return (u16)(r >> 16);
}
__device__ __forceinline__ float gelu_fast(float v){
    const float u = 1.5957691216f * v * (1.0f + 0.044715f * v * v);
    const float e = __expf(u);
    return v * (1.0f - 1.0f / (e + 1.0f));
}
#define GLOAD16(src, dst) __builtin_amdgcn_global_load_lds( \
    (const __attribute__((address_space(1))) void*)(src),   \
    (__attribute__((address_space(3))) void*)(dst), 16, 0, 0)
#define SCHED0 __builtin_amdgcn_sched_barrier(0)

// ---------------------------------------------------------------------------
// gemm64: C[M,N] = A[M,K] @ B[K,N] (+bias +res, opt GELU). 64x128 tile,
// BK=64, 4 waves, 16 MFMA/step, counted-vmcnt double buffer.
// LDS (row, c) holds global chunk (row, c ^ (row&7)); ds_read XORs the same.
// blockIdx.x = m-tile (XCD A-panel reuse), blockIdx.y = n-tile.
// AF32: f32 A, depth-2 register prefetch. A2/ksplit: concat A at k=ksplit.
// PART: z = k-chunk (kch%64==0), f32 partials at Cout+z*czs. Else z = batch.
// ---------------------------------------------------------------------------
template<bool GELU, bool RES, bool AF32, bool OUTF32, bool PART>
__global__ __launch_bounds__(256) void gemm64(
    const void* __restrict__ A, const void* __restrict__ A2, int ksplit,
    const u16* __restrict__ Bt, const float* __restrict__ bias,
    const u16* __restrict__ res, int ldr,
    void* __restrict__ Cout, int K, int lda, int ldb, int ldc,
    long azs, long bzs, int biaszs, long czs, int kch)
{
    __shared__ __align__(16) u16 As[2][64 * 64];
    __shared__ __align__(16) u16 Bs[2][128 * 64];
    const int tid = threadIdx.x;
    const int w = tid >> 6, l = tid & 63;
    const int wr = w >> 1, wc = w & 1;
    const int m0 = blockIdx.x * 64, n0 = blockIdx.y * 128;
    const int z = blockIdx.z;
    int kbeg = 0, kend = K;
    if (PART) { kbeg = z * kch; kend = min(kbeg + kch, K); }
    const u16* A16 = (const u16*)A + (PART ? 0 : (size_t)z * azs);
    const float* Af = (const float*)A;
    const u16* BtZ = Bt + (PART ? 0 : (size_t)z * bzs);
    const int swc = (l & 7) ^ (l >> 3);   // pre-swizzled source chunk

    f32x4 acc[2][4];
#pragma unroll
    for (int i = 0; i < 2; ++i)
#pragma unroll
        for (int j = 0; j < 4; ++j) acc[i][j] = (f32x4){0.f, 0.f, 0.f, 0.f};

    auto stageB = [&](int buf, int k0) {
#pragma unroll
        for (int j = 0; j < 4; ++j) {
            const int rb = w * 32 + j * 8;
            const u16* gb = BtZ + (size_t)(n0 + rb + (l >> 3)) * ldb + k0 + swc * 8;
            GLOAD16(gb, &Bs[buf][rb * 64]);
        }
    };
    auto stageA16 = [&](int buf, int k0) {
        const u16* base = (k0 >= ksplit) ? ((const u16*)A2 + (k0 - ksplit)) : (A16 + k0);
#pragma unroll
        for (int j = 0; j < 2; ++j) {
            const int rb = w * 16 + j * 8;
            const u16* ga = base + (size_t)(m0 + rb + (l >> 3)) * lda + swc * 8;
            GLOAD16(ga, &As[buf][rb * 64]);
        }
    };
    auto loadA = [&](int k0, float4& p0, float4& p1, float4& p2, float4& p3) {
        const float* g = Af + (size_t)(m0 + (tid >> 2)) * lda + k0 + (tid & 3) * 16;
        p0 = *(const float4*)g;       p1 = *(const float4*)(g + 4);
        p2 = *(const float4*)(g + 8); p3 = *(const float4*)(g + 12);
    };
    auto writeA = [&](const float4& p0, const float4& p1, const float4& p2,
                      const float4& p3, int buf) {
        const int row = tid >> 2, c0 = (tid & 3) * 2;
        u16x8 v0, v1;
        v0[0] = f2bf(p0.x); v0[1] = f2bf(p0.y); v0[2] = f2bf(p0.z); v0[3] = f2bf(p0.w);
        v0[4] = f2bf(p1.x); v0[5] = f2bf(p1.y); v0[6] = f2bf(p1.z); v0[7] = f2bf(p1.w);
        v1[0] = f2bf(p2.x); v1[1] = f2bf(p2.y); v1[2] = f2bf(p2.z); v1[3] = f2bf(p2.w);
        v1[4] = f2bf(p3.x); v1[5] = f2bf(p3.y); v1[6] = f2bf(p3.z); v1[7] = f2bf(p3.w);
        *(u16x8*)&As[buf][row * 64 + ((c0)     ^ (row & 7)) * 8] = v0;
        *(u16x8*)&As[buf][row * 64 + ((c0 + 1) ^ (row & 7)) * 8] = v1;
    };
    int cur = 0;
    auto compute = [&]() {
#pragma unroll
        for (int kk = 0; kk < 2; ++kk) {
            const int kcb = kk * 4 + (l >> 4);
            bf16x8 a[2], b[4];
#pragma unroll
            for (int i = 0; i < 2; ++i) {
                const int row = wr * 32 + i * 16 + (l & 15);
                a[i] = *(const bf16x8*)&As[cur][row * 64 + (kcb ^ (l & 7)) * 8];
            }
#pragma unroll
            for (int j = 0; j < 4; ++j) {
                const int row = wc * 64 + j * 16 + (l & 15);
                b[j] = *(const bf16x8*)&Bs[cur][row * 64 + (kcb ^ (l & 7)) * 8];
            }
#pragma unroll
            for (int i = 0; i < 2; ++i)
#pragma unroll
                for (int j = 0; j < 4; ++j)
                    acc[i][j] = __builtin_amdgcn_mfma_f32_16x16x32_bf16(a[i], b[j], acc[i][j], 0, 0, 0);
        }
    };

    const int nt = (kend - kbeg) >> 6;
    if (AF32) {
        float4 a0, a1, a2, a3, b0, b1, b2, b3;
        loadA(kbeg, a0, a1, a2, a3);
        stageB(0, kbeg);
        if (nt > 1) {
            loadA(kbeg + 64, b0, b1, b2, b3);
            asm volatile("s_waitcnt vmcnt(4)" ::: "memory");
        } else {
            asm volatile("s_waitcnt vmcnt(0)" ::: "memory");
        }
        writeA(a0, a1, a2, a3, 0);
        asm volatile("s_waitcnt lgkmcnt(0)" ::: "memory");
        auto stepA = [&](int t, float4& w0, float4& w1, float4& w2, float4& w3,
                         float4& l0, float4& l1, float4& l2, float4& l3) {
            const bool ldA = (t + 2) < nt;
            const bool stB = (t + 1) < nt;
            if (ldA) loadA(kbeg + ((t + 2) << 6), l0, l1, l2, l3);
            if (stB) stageB(cur ^ 1, kbeg + ((t + 1) << 6));
            if (ldA)      asm volatile("s_waitcnt vmcnt(8)" ::: "memory");
            else if (stB) asm volatile("s_waitcnt vmcnt(4)" ::: "memory");
            else          asm volatile("s_waitcnt vmcnt(0)" ::: "memory");
            SCHED0;
            __builtin_amdgcn_s_barrier();
            SCHED0;
            compute();
            if (stB) writeA(w0, w1, w2, w3, cur ^ 1);
            asm volatile("s_waitcnt lgkmcnt(0)" ::: "memory");
            SCHED0;
            __builtin_amdgcn_s_barrier();
            SCHED0;
            cur ^= 1;
        };
        int t = 0;
        while (t + 2 <= nt) {
            stepA(t,     b0, b1, b2, b3, a0, a1, a2, a3);
            stepA(t + 1, a0, a1, a2, a3, b0, b1, b2, b3);
            t += 2;
        }
        if (t < nt) stepA(t, b0, b1, b2, b3, a0, a1, a2, a3);
    } else {
        stageA16(0, kbeg);
        stageB(0, kbeg);
        for (int t = 0; t < nt; ++t) {
            const bool more = (t + 1) < nt;
            if (more) {
                const int kn = kbeg + ((t + 1) << 6);
                stageA16(cur ^ 1, kn);
                stageB(cur ^ 1, kn);
            }
            if (more) asm volatile("s_waitcnt vmcnt(6)" ::: "memory");
            else      asm volatile("s_waitcnt vmcnt(0)" ::: "memory");
            SCHED0;
            __builtin_amdgcn_s_barrier();
            SCHED0;
            compute();
            asm volatile("" ::: "memory");
            SCHED0;
            __builtin_amdgcn_s_barrier();
            SCHED0;
            cur ^= 1;
        }
    }

    // epilogue: C/D layout col = l&15, row = (l>>4)*4 + r  [m89/m91]
    float* cF = (float*)Cout + (size_t)z * czs;
    u16*   cH = (u16*)Cout + (size_t)z * czs;
    const float* biasZ = (!PART && bias) ? bias + (size_t)z * biaszs : nullptr;
#pragma unroll
    for (int i = 0; i < 2; ++i) {
#pragma unroll
        for (int j = 0; j < 4; ++j) {
            const int col = n0 + wc * 64 + j * 16 + (l & 15);
            const int rowb = m0 + wr * 32 + i * 16 + (l >> 4) * 4;
#pragma unroll
            for (int r = 0; r < 4; ++r) {
                const int row = rowb + r;
                float v = acc[i][j][r];
                if (PART) {
                    cF[(size_t)row * ldc + col] = v;
                } else {
                    if (biasZ) v += biasZ[col];
                    if (RES) v += bf2f(res[(size_t)row * ldr + col]);
                    if (GELU) v = gelu_fast(v);
                    if (OUTF32) cF[(size_t)row * ldc + col] = v;
                    else        cH[(size_t)row * ldc + col] = f2bf(v);
                }
            }
        }
    }
}

// ---------------------------------------------------------------------------
// reduceLN512: fused split-K reduce + bias (+res) -> optional bf16 H-write,
// then row LayerNorm (512 cols) -> bf16 T-write. One wave per row.
// ---------------------------------------------------------------------------
template<int NP, bool RES, bool WRITEH>
__global__ __launch_bounds__(256) void reduceLN512(
    const float* __restrict__ part, long pzs, const float* __restrict__ bias,
    const u16* __restrict__ res, const float* __restrict__ g,
    const float* __restrict__ b, u16* __restrict__ outH, u16* __restrict__ outT)
{
    const int wid = threadIdx.x >> 6, l = threadIdx.x & 63;
    const size_t row = (size_t)blockIdx.x * 4 + wid;
    const size_t base = row * 512 + l * 8;
    float f[8];
    {
        const float4 p0 = *(const float4*)(part + base);
        const float4 p1 = *(const float4*)(part + base + 4);
        f[0]=p0.x; f[1]=p0.y; f[2]=p0.z; f[3]=p0.w;
        f[4]=p1.x; f[5]=p1.y; f[6]=p1.z; f[7]=p1.w;
    }
#pragma unroll
    for (int p = 1; p < NP; ++p) {
        const float4 p0 = *(const float4*)(part + (size_t)p * pzs + base);
        const float4 p1 = *(const float4*)(part + (size_t)p * pzs + base + 4);
        f[0]+=p0.x; f[1]+=p0.y; f[2]+=p0.z; f[3]+=p0.w;
        f[4]+=p1.x; f[5]+=p1.y; f[6]+=p1.z; f[7]+=p1.w;
    }
    {
        const float4 b0 = *(const float4*)(bias + l * 8);
        const float4 b1 = *(const float4*)(bias + l * 8 + 4);
        f[0]+=b0.x; f[1]+=b0.y; f[2]+=b0.z; f[3]+=b0.w;
        f[4]+=b1.x; f[5]+=b1.y; f[6]+=b1.z; f[7]+=b1.w;
    }
    if (RES) {
        const u16x8 r = *(const u16x8*)(res + base);
#pragma unroll
        for (int j = 0; j < 8; ++j) f[j] += bf2f(r[j]);
    }
    if (WRITEH) {
        u16x8 h;
#pragma unroll
        for (int j = 0; j < 8; ++j) h[j] = f2bf(f[j]);
        *(u16x8*)(outH + base) = h;
    }
    float s = 0.f, q = 0.f;
#pragma unroll
    for (int j = 0; j < 8; ++j) { s += f[j]; q += f[j] * f[j]; }
#pragma unroll
    for (int o = 32; o > 0; o >>= 1) { s += __shfl_xor(s, o); q += __shfl_xor(q, o); }
    const float mean = s * (1.f / 512.f);
    const float var = q * (1.f / 512.f) - mean * mean;
    const float rstd = rsqrtf(var + 1e-5f);
    u16x8 t;
#pragma unroll
    for (int j = 0; j < 8; ++j) {
        const int c = l * 8 + j;
        t[j] = f2bf((f[j] - mean) * rstd * g[c] + b[c]);
    }
    *(u16x8*)(outT + base) = t;
}

// per-head LN over 256 (rows are [8192,768], heads of 256), wave per (row,head)
__global__ __launch_bounds__(256) void lnh_kernel(
    const u16* __restrict__ in, const float* __restrict__ g,
    const float* __restrict__ b, u16* __restrict__ out)
{
    const int wid = threadIdx.x >> 6, l = threadIdx.x & 63;
    const int unit = blockIdx.x * 4 + wid;        // unit = h*8192 + row
    const int h = unit >> 13, row = unit & 8191;
    const size_t base = (size_t)row * 768 + h * 256 + l * 4;
    u16x4 v = *(const u16x4*)(in + base);
    float f[4], s = 0.f, q = 0.f;
#pragma unroll
    for (int j = 0; j < 4; ++j) { f[j] = bf2f(v[j]); s += f[j]; q += f[j] * f[j]; }
#pragma unroll
    for (int o = 32; o > 0; o >>= 1) { s += __shfl_xor(s, o); q += __shfl_xor(q, o); }
    const float mean = s * (1.f / 256.f);
    const float var = q * (1.f / 256.f) - mean * mean;
    const float rstd = rsqrtf(var + 1e-5f);
    u16x4 ov;
#pragma unroll
    for (int j = 0; j < 4; ++j) {
        const int c = h * 256 + l * 4 + j;
        ov[j] = f2bf((f[j] - mean) * rstd * g[c] + b[c]);
    }
    *(u16x4*)(out + base) = ov;
}

// ---------------------------------------------------------------------------
// prep_all: ALL weight prep in one launch (block-range dispatch, 9096 blocks)
// seg layout: [0,2048) w_inT | [,3072) wff1t | [,4096) wff2t | [,4352) woTca
// | [,4608) woTsa | [,6144) Wh1t | [,8832) Wh2t | [,8960) cvt wv_ca
// | [,9088) cvt wv_sa | [,9096) bias prep.
// ---------------------------------------------------------------------------
struct PrepPtrs {
    const float *w_in, *w_ff1, *w_ff2, *wo_ca, *wo_sa, *wv_ca, *wv_sa;
    const float *wh1, *wh2, *b_in, *pos, *bv_sa, *bo_sa, *bv_ca, *bo_ca;
    u16 *w_inT, *wff1t, *wff2t, *woT2, *wv2b, *Wh1t, *Wh2t;
    float *bias_in, *b_comb;
};

__device__ __forceinline__ void dev_transpose(
    const float* in, u16* out, int K, int N, int t, int tid, u16 (*tile)[33])
{
    const int nt = N >> 5;
    const int n0 = (t % nt) * 32, k0 = (t / nt) * 32;
    const int tx = tid & 31, ty = tid >> 5;
#pragma unroll
    for (int i = 0; i < 32; i += 8)
        tile[ty + i][tx] = f2bf(in[(size_t)(k0 + ty + i) * N + (n0 + tx)]);
    __syncthreads();
#pragma unroll
    for (int i = 0; i < 32; i += 8)
        out[(size_t)(n0 + ty + i) * K + (k0 + tx)] = tile[tx][ty + i];
}

__global__ __launch_bounds__(256) void prep_all(PrepPtrs p)
{
    __shared__ u16 tile[32][33];
    __shared__ float psa[4][64], pca[4][64];
    const int tid = threadIdx.x;
    int b = blockIdx.x;
    if (b < 2048) { dev_transpose(p.w_in, p.w_inT, 4096, 512, b, tid, tile); return; }
    b -= 2048;
    if (b < 1024) { dev_transpose(p.w_ff1, p.wff1t, 512, 2048, b, tid, tile); return; }
    b -= 1024;
    if (b < 1024) { dev_transpose(p.w_ff2, p.wff2t, 2048, 512, b, tid, tile); return; }
    b -= 1024;
    if (b < 256) { dev_transpose(p.wo_ca, p.woT2, 512, 512, b, tid, tile); return; }
    b -= 256;
    if (b < 256) { dev_transpose(p.wo_sa, p.woT2 + 512 * 512, 512, 512, b, tid, tile); return; }
    b -= 256;
    if (b < 1536) {  // Wh1t[h*256+k][d] = wh1[h][d][k]
        const int idx = b * 256 + tid;
        const int d = idx & 511, j = idx >> 9;
        const int h = j >> 8, kk = j & 255;
        p.Wh1t[idx] = f2bf(p.wh1[((size_t)(h * 512 + d)) * 256 + kk]);
        return;
    }
    b -= 1536;
    if (b < 2688) {  // Wh2t[h][o][k] = wh2[h][k][o]
        const int idx = b * 256 + tid;
        const int kk = idx & 255, t = idx >> 8;
        const int h = t / 896, o = t - h * 896;
        p.Wh2t[idx] = f2bf(p.wh2[((size_t)(h * 256 + kk)) * 896 + o]);
        return;
    }
    b -= 2688;
    if (b < 256) {   // cvt wv_ca (128 blocks) then wv_sa (128 blocks)
        const float* src = (b < 128) ? p.wv_ca : p.wv_sa;
        u16* dst = p.wv2b + (b < 128 ? 0 : 512 * 512);
        const int i = (b & 127) * 256 + tid;
        const float4* q = (const float4*)src + (size_t)i * 2;
        const float4 a = q[0], c = q[1];
        u16x8 v;
        v[0] = f2bf(a.x); v[1] = f2bf(a.y); v[2] = f2bf(a.z); v[3] = f2bf(a.w);
        v[4] = f2bf(c.x); v[5] = f2bf(c.y); v[6] = f2bf(c.z); v[7] = f2bf(c.w);
        *(u16x8*)(dst + (size_t)i * 8) = v;
        return;
    }
    b -= 256;
    {   // bias prep: 8 blocks, block b covers i in [b*64, b*64+64)
        const int ii = tid & 63, kg = tid >> 6;
        const int i = b * 64 + ii;
        float sa = 0.f, ca = 0.f;
        for (int k = kg; k < 512; k += 4) {
            sa += p.bv_sa[k] * p.wo_sa[(size_t)k * 512 + i];
            ca += p.bv_ca[k] * p.wo_ca[(size_t)k * 512 + i];
        }
        psa[kg][ii] = sa; pca[kg][ii] = ca;
        __syncthreads();
        if (kg == 0) {
            p.bias_in[i] = p.b_in[i] + p.pos[i];
            p.b_comb[i] = psa[0][ii] + psa[1][ii] + psa[2][ii] + psa[3][ii]
                        + pca[0][ii] + pca[1][ii] + pca[2][ii] + pca[3][ii]
                        + p.bo_sa[i] + p.bo_ca[i];
        }
    }
}

extern "C" void kernel_launch(void* const* d_in, const int* in_sizes, int n_in,
                              void* d_out, int out_size, void* d_ws, size_t ws_size,
                              hipStream_t stream)
{
    const float* x      = (const float*)d_in[0];
    const float* ln1_g  = (const float*)d_in[4];
    const float* ln1_b  = (const float*)d_in[5];
    const float* ln3_g  = (const float*)d_in[16];
    const float* ln3_b  = (const float*)d_in[17];
    const float* b_ff1  = (const float*)d_in[19];
    const float* b_ff2  = (const float*)d_in[21];
    const float* lnoutg = (const float*)d_in[22];
    const float* lnoutb = (const float*)d_in[23];
    const float* bh1    = (const float*)d_in[25];
    const float* lnh_g  = (const float*)d_in[26];
    const float* lnh_b  = (const float*)d_in[27];
    const float* bh2    = (const float*)d_in[29];
    float* out = (float*)d_out;
    const int KBIG = 0x7fffffff;

    // ---- workspace layout (~70 MB, rewritten fully every call) ----
    char* wsp = (char*)d_ws;
    size_t off = 0;
    auto ALLOC = [&](size_t n) { char* r = wsp + off; off = (off + n + 255) & ~(size_t)255; return r; };
    u16* w_inT  = (u16*)ALLOC(512UL * 4096 * 2);
    u16* wff1t  = (u16*)ALLOC(2048UL * 512 * 2);
    u16* wff2t  = (u16*)ALLOC(512UL * 2048 * 2);
    u16* woT2   = (u16*)ALLOC(2UL * 512 * 512 * 2);
    u16* wv2b   = (u16*)ALLOC(2UL * 512 * 512 * 2);
    u16* Wct    = (u16*)ALLOC(512UL * 1024 * 2);
    u16* Wh1t   = (u16*)ALLOC(768UL * 512 * 2);
    u16* Wh2t   = (u16*)ALLOC(3UL * 896 * 256 * 2);
    float* bias_in = (float*)ALLOC(512 * 4);
    float* b_comb  = (float*)ALLOC(512 * 4);
    u16* h0   = (u16*)ALLOC(8192UL * 512 * 2);
    u16* T    = (u16*)ALLOC(8192UL * 512 * 2);
    u16* hbuf = (u16*)ALLOC(8192UL * 512 * 2);
    u16* G    = (u16*)ALLOC(8192UL * 2048 * 2);
    u16* Z  = G;
    u16* Z2 = (u16*)((char*)G + 8192UL * 768 * 2);
    float* partO = out;                    // split-K partials in d_out
    const long PZS = 8192L * 512;

    // ---- consolidated weight prep (1 launch) ----
    PrepPtrs pp;
    pp.w_in = (const float*)d_in[1];  pp.w_ff1 = (const float*)d_in[18];
    pp.w_ff2 = (const float*)d_in[20];
    pp.wo_ca = (const float*)d_in[14]; pp.wo_sa = (const float*)d_in[8];
    pp.wv_ca = (const float*)d_in[12]; pp.wv_sa = (const float*)d_in[6];
    pp.wh1 = (const float*)d_in[24];   pp.wh2 = (const float*)d_in[28];
    pp.b_in = (const float*)d_in[2];   pp.pos = (const float*)d_in[3];
    pp.bv_sa = (const float*)d_in[7];  pp.bo_sa = (const float*)d_in[9];
    pp.bv_ca = (const float*)d_in[13]; pp.bo_ca = (const float*)d_in[15];
    pp.w_inT = w_inT; pp.wff1t = wff1t; pp.wff2t = wff2t;
    pp.woT2 = woT2; pp.wv2b = wv2b; pp.Wh1t = Wh1t; pp.Wh2t = Wh2t;
    pp.bias_in = bias_in; pp.b_comb = b_comb;
    prep_all<<<9096, 256, 0, stream>>>(pp);
    // Wct (z-batched): z=0 -> ca half (k<512), z=1 -> sa half (k>=512)
    gemm64<false, false, false, false, false><<<dim3(8, 4, 2), 256, 0, stream>>>(
        woT2, nullptr, KBIG, wv2b, nullptr, nullptr, 0, Wct,
        512, 512, 512, 1024, 512 * 512, 512 * 512, 0, 512, 0);

    // ---- main pipeline ----
    // GEMM1 split-K x3 -> partials in d_out; fused reduce+bias -> h0, T=ln1
    gemm64<false, false, true, false, true><<<dim3(128, 4, 3), 256, 0, stream>>>(
        x, nullptr, KBIG, w_inT, nullptr, nullptr, 0, partO,
        4096, 4096, 4096, 512, 0, 0, 0, PZS, 1408);
    reduceLN512<3, false, true><<<2048, 256, 0, stream>>>(
        partO, PZS, bias_in, nullptr, ln1_g, ln1_b, h0, T);
    // attention split-K x2: [h0 | T] @ Wct -> partials; fused reduce +b_comb
    // +h0 residual -> hbuf=h2, T=ln3
    gemm64<false, false, false, false, true><<<dim3(128, 4, 2), 256, 0, stream>>>(
        h0, T, 512, Wct, nullptr, nullptr, 0, partO,
        1024, 512, 1024, 512, 0, 0, 0, PZS, 512);
    reduceLN512<2, true, true><<<2048, 256, 0, stream>>>(
        partO, PZS, b_comb, h0, ln3_g, ln3_b, hbuf, T);
    // G = gelu(T @ w_ff1 + b_ff1)   [8192, 2048]
    gemm64<true, false, false, false, false><<<dim3(128, 16), 256, 0, stream>>>(
        T, nullptr, KBIG, wff1t, b_ff1, nullptr, 0, G,
        512, 512, 512, 2048, 0, 0, 0, 0, 0);
    // FF2 split-K x2 -> partials; fused reduce +b_ff2 +h2 residual -> T=lnout
    gemm64<false, false, false, false, true><<<dim3(128, 4, 2), 256, 0, stream>>>(
        G, nullptr, KBIG, wff2t, nullptr, nullptr, 0, partO,
        2048, 2048, 2048, 512, 0, 0, 0, PZS, 1024);
    reduceLN512<2, true, false><<<2048, 256, 0, stream>>>(
        partO, PZS, b_ff2, hbuf, lnoutg, lnoutb, nullptr, T);
    // Z = gelu(T @ Wh1 + bh1)   [8192, 768]
    gemm64<true, false, false, false, false><<<dim3(128, 6), 256, 0, stream>>>(
        T, nullptr, KBIG, Wh1t, bh1, nullptr, 0, Z,
        512, 512, 512, 768, 0, 0, 0, 0, 0);
    // Z2 = per-head LN(Z)
    lnh_kernel<<<6144, 256, 0, stream>>>(Z, lnh_g, lnh_b, Z2);
    // out[:, z*896:(z+1)*896] = Z2[:, z*256:+256] @ wh2[z] + bh2[z]
    // (f32, z-batched; overwrites ALL partial scratch in d_out)
    gemm64<false, false, false, true, false><<<dim3(128, 7, 3), 256, 0, stream>>>(
        Z2, nullptr, KBIG, Wh2t, bh2, nullptr, 0, out,
        256, 768, 256, 2688, 256, 896 * 256, 896, 896, 0);
}

// Round 19
// 333.460 us; speedup vs baseline: 1.2756x; 1.0159x over previous
//
#include <hip/hip_runtime.h>
#include <math.h>

// ---------------------------------------------------------------------------
// RFSQDraftModelWithProjection — f32 in / f32 out, bf16 MFMA compute.
// r19: x pre-converted to bf16 inside prep_all (xbf lives in d_out, dead
// after GEMM1) -> GEMM1 runs the plain bf16 global_load_lds path (half the
// A-bytes, no in-loop f2bf). GEMM1/attn partials x2 in G; FF2 partials in
// d_out. Otherwise r18: BK=64, both-sides XOR swizzle (0 conflicts),
// counted vmcnt, fused reduceLN, fast GELU, single prep mega-kernel.
// ---------------------------------------------------------------------------

typedef unsigned short u16;
typedef __attribute__((ext_vector_type(8))) short bf16x8;
typedef __attribute__((ext_vector_type(4))) float f32x4;
typedef __attribute__((ext_vector_type(8))) unsigned short u16x8;
typedef __attribute__((ext_vector_type(4))) unsigned short u16x4;

__device__ __forceinline__ float bf2f(u16 u){
    union { unsigned int i; float f; } x; x.i = ((unsigned int)u) << 16; return x.f;
}
__device__ __forceinline__ u16 f2bf(float f){
    union { float f; unsigned int i; } x; x.f = f;
    unsigned int r = x.i + 0x7fffu + ((x.i >> 16) & 1u);
    return (u16)(r >> 16);
}
__device__ __forceinline__ float gelu_fast(float v){
    const float u = 1.5957691216f * v * (1.0f + 0.044715f * v * v);
    const float e = __expf(u);
    return v * (1.0f - 1.0f / (e + 1.0f));
}
#define GLOAD16(src, dst) __builtin_amdgcn_global_load_lds( \
    (const __attribute__((address_space(1))) void*)(src),   \
    (__attribute__((address_space(3))) void*)(dst), 16, 0, 0)
#define SCHED0 __builtin_amdgcn_sched_barrier(0)

// ---------------------------------------------------------------------------
// gemm64: C[M,N] = A[M,K] @ B[K,N] (+bias +res, opt GELU). 64x128 tile,
// BK=64, 4 waves, 16 MFMA/step, counted-vmcnt double buffer.
// LDS (row, c) holds global chunk (row, c ^ (row&7)); ds_read XORs the same.
// blockIdx.x = m-tile (XCD A-panel reuse), blockIdx.y = n-tile.
// A2/ksplit: concat A at k=ksplit (64 | ksplit).  PART: z = k-chunk
// (kch%64==0), f32 partials at Cout+z*czs.  Else z = batch via strides.
// ---------------------------------------------------------------------------
template<bool GELU, bool RES, bool OUTF32, bool PART>
__global__ __launch_bounds__(256) void gemm64(
    const u16* __restrict__ A, const u16* __restrict__ A2, int ksplit,
    const u16* __restrict__ Bt, const float* __restrict__ bias,
    const u16* __restrict__ res, int ldr,
    void* __restrict__ Cout, int K, int lda, int ldb, int ldc,
    long azs, long bzs, int biaszs, long czs, int kch)
{
    __shared__ __align__(16) u16 As[2][64 * 64];
    __shared__ __align__(16) u16 Bs[2][128 * 64];
    const int tid = threadIdx.x;
    const int w = tid >> 6, l = tid & 63;
    const int wr = w >> 1, wc = w & 1;
    const int m0 = blockIdx.x * 64, n0 = blockIdx.y * 128;
    const int z = blockIdx.z;
    int kbeg = 0, kend = K;
    if (PART) { kbeg = z * kch; kend = min(kbeg + kch, K); }
    const u16* A16 = A + (PART ? 0 : (size_t)z * azs);
    const u16* BtZ = Bt + (PART ? 0 : (size_t)z * bzs);
    const int swc = (l & 7) ^ (l >> 3);   // pre-swizzled source chunk

    f32x4 acc[2][4];
#pragma unroll
    for (int i = 0; i < 2; ++i)
#pragma unroll
        for (int j = 0; j < 4; ++j) acc[i][j] = (f32x4){0.f, 0.f, 0.f, 0.f};

    auto stageB = [&](int buf, int k0) {
#pragma unroll
        for (int j = 0; j < 4; ++j) {
            const int rb = w * 32 + j * 8;
            const u16* gb = BtZ + (size_t)(n0 + rb + (l >> 3)) * ldb + k0 + swc * 8;
            GLOAD16(gb, &Bs[buf][rb * 64]);
        }
    };
    auto stageA16 = [&](int buf, int k0) {
        const u16* base = (k0 >= ksplit) ? (A2 + (k0 - ksplit)) : (A16 + k0);
#pragma unroll
        for (int j = 0; j < 2; ++j) {
            const int rb = w * 16 + j * 8;
            const u16* ga = base + (size_t)(m0 + rb + (l >> 3)) * lda + swc * 8;
            GLOAD16(ga, &As[buf][rb * 64]);
        }
    };
    int cur = 0;
    auto compute = [&]() {
#pragma unroll
        for (int kk = 0; kk < 2; ++kk) {
            const int kcb = kk * 4 + (l >> 4);
            bf16x8 a[2], b[4];
#pragma unroll
            for (int i = 0; i < 2; ++i) {
                const int row = wr * 32 + i * 16 + (l & 15);
                a[i] = *(const bf16x8*)&As[cur][row * 64 + (kcb ^ (l & 7)) * 8];
            }
#pragma unroll
            for (int j = 0; j < 4; ++j) {
                const int row = wc * 64 + j * 16 + (l & 15);
                b[j] = *(const bf16x8*)&Bs[cur][row * 64 + (kcb ^ (l & 7)) * 8];
            }
#pragma unroll
            for (int i = 0; i < 2; ++i)
#pragma unroll
                for (int j = 0; j < 4; ++j)
                    acc[i][j] = __builtin_amdgcn_mfma_f32_16x16x32_bf16(a[i], b[j], acc[i][j], 0, 0, 0);
        }
    };

    const int nt = (kend - kbeg) >> 6;
    stageA16(0, kbeg);
    stageB(0, kbeg);
    for (int t = 0; t < nt; ++t) {
        const bool more = (t + 1) < nt;
        if (more) {
            const int kn = kbeg + ((t + 1) << 6);
            stageA16(cur ^ 1, kn);
            stageB(cur ^ 1, kn);
        }
        if (more) asm volatile("s_waitcnt vmcnt(6)" ::: "memory");
        else      asm volatile("s_waitcnt vmcnt(0)" ::: "memory");
        SCHED0;
        __builtin_amdgcn_s_barrier();
        SCHED0;
        compute();
        asm volatile("" ::: "memory");
        SCHED0;
        __builtin_amdgcn_s_barrier();
        SCHED0;
        cur ^= 1;
    }

    // epilogue: C/D layout col = l&15, row = (l>>4)*4 + r  [m89/m91]
    float* cF = (float*)Cout + (size_t)z * czs;
    u16*   cH = (u16*)Cout + (size_t)z * czs;
    const float* biasZ = (!PART && bias) ? bias + (size_t)z * biaszs : nullptr;
#pragma unroll
    for (int i = 0; i < 2; ++i) {
#pragma unroll
        for (int j = 0; j < 4; ++j) {
            const int col = n0 + wc * 64 + j * 16 + (l & 15);
            const int rowb = m0 + wr * 32 + i * 16 + (l >> 4) * 4;
#pragma unroll
            for (int r = 0; r < 4; ++r) {
                const int row = rowb + r;
                float v = acc[i][j][r];
                if (PART) {
                    cF[(size_t)row * ldc + col] = v;
                } else {
                    if (biasZ) v += biasZ[col];
                    if (RES) v += bf2f(res[(size_t)row * ldr + col]);
                    if (GELU) v = gelu_fast(v);
                    if (OUTF32) cF[(size_t)row * ldc + col] = v;
                    else        cH[(size_t)row * ldc + col] = f2bf(v);
                }
            }
        }
    }
}

// ---------------------------------------------------------------------------
// reduceLN512: fused split-K reduce + bias (+res) -> optional bf16 H-write,
// then row LayerNorm (512 cols) -> bf16 T-write. One wave per row.
// ---------------------------------------------------------------------------
template<int NP, bool RES, bool WRITEH>
__global__ __launch_bounds__(256) void reduceLN512(
    const float* __restrict__ part, long pzs, const float* __restrict__ bias,
    const u16* __restrict__ res, const float* __restrict__ g,
    const float* __restrict__ b, u16* __restrict__ outH, u16* __restrict__ outT)
{
    const int wid = threadIdx.x >> 6, l = threadIdx.x & 63;
    const size_t row = (size_t)blockIdx.x * 4 + wid;
    const size_t base = row * 512 + l * 8;
    float f[8];
    {
        const float4 p0 = *(const float4*)(part + base);
        const float4 p1 = *(const float4*)(part + base + 4);
        f[0]=p0.x; f[1]=p0.y; f[2]=p0.z; f[3]=p0.w;
        f[4]=p1.x; f[5]=p1.y; f[6]=p1.z; f[7]=p1.w;
    }
#pragma unroll
    for (int p = 1; p < NP; ++p) {
        const float4 p0 = *(const float4*)(part + (size_t)p * pzs + base);
        const float4 p1 = *(const float4*)(part + (size_t)p * pzs + base + 4);
        f[0]+=p0.x; f[1]+=p0.y; f[2]+=p0.z; f[3]+=p0.w;
        f[4]+=p1.x; f[5]+=p1.y; f[6]+=p1.z; f[7]+=p1.w;
    }
    {
        const float4 b0 = *(const float4*)(bias + l * 8);
        const float4 b1 = *(const float4*)(bias + l * 8 + 4);
        f[0]+=b0.x; f[1]+=b0.y; f[2]+=b0.z; f[3]+=b0.w;
        f[4]+=b1.x; f[5]+=b1.y; f[6]+=b1.z; f[7]+=b1.w;
    }
    if (RES) {
        const u16x8 r = *(const u16x8*)(res + base);
#pragma unroll
        for (int j = 0; j < 8; ++j) f[j] += bf2f(r[j]);
    }
    if (WRITEH) {
        u16x8 h;
#pragma unroll
        for (int j = 0; j < 8; ++j) h[j] = f2bf(f[j]);
        *(u16x8*)(outH + base) = h;
    }
    float s = 0.f, q = 0.f;
#pragma unroll
    for (int j = 0; j < 8; ++j) { s += f[j]; q += f[j] * f[j]; }
#pragma unroll
    for (int o = 32; o > 0; o >>= 1) { s += __shfl_xor(s, o); q += __shfl_xor(q, o); }
    const float mean = s * (1.f / 512.f);
    const float var = q * (1.f / 512.f) - mean * mean;
    const float rstd = rsqrtf(var + 1e-5f);
    u16x8 t;
#pragma unroll
    for (int j = 0; j < 8; ++j) {
        const int c = l * 8 + j;
        t[j] = f2bf((f[j] - mean) * rstd * g[c] + b[c]);
    }
    *(u16x8*)(outT + base) = t;
}

// per-head LN over 256 (rows are [8192,768], heads of 256), wave per (row,head)
__global__ __launch_bounds__(256) void lnh_kernel(
    const u16* __restrict__ in, const float* __restrict__ g,
    const float* __restrict__ b, u16* __restrict__ out)
{
    const int wid = threadIdx.x >> 6, l = threadIdx.x & 63;
    const int unit = blockIdx.x * 4 + wid;        // unit = h*8192 + row
    const int h = unit >> 13, row = unit & 8191;
    const size_t base = (size_t)row * 768 + h * 256 + l * 4;
    u16x4 v = *(const u16x4*)(in + base);
    float f[4], s = 0.f, q = 0.f;
#pragma unroll
    for (int j = 0; j < 4; ++j) { f[j] = bf2f(v[j]); s += f[j]; q += f[j] * f[j]; }
#pragma unroll
    for (int o = 32; o > 0; o >>= 1) { s += __shfl_xor(s, o); q += __shfl_xor(q, o); }
    const float mean = s * (1.f / 256.f);
    const float var = q * (1.f / 256.f) - mean * mean;
    const float rstd = rsqrtf(var + 1e-5f);
    u16x4 ov;
#pragma unroll
    for (int j = 0; j < 4; ++j) {
        const int c = h * 256 + l * 4 + j;
        ov[j] = f2bf((f[j] - mean) * rstd * g[c] + b[c]);
    }
    *(u16x4*)(out + base) = ov;
}

// ---------------------------------------------------------------------------
// prep_all: ALL prep in one launch (block-range dispatch, 25480 blocks).
// [0,16384) cvt x->xbf | [,18432) w_inT | [,19456) wff1t | [,20480) wff2t
// | [,20736) woTca | [,20992) woTsa | [,22528) Wh1t | [,25216) Wh2t
// | [,25472) cvt wv_ca/wv_sa | [,25480) bias prep.
// ---------------------------------------------------------------------------
struct PrepPtrs {
    const float *x, *w_in, *w_ff1, *w_ff2, *wo_ca, *wo_sa, *wv_ca, *wv_sa;
    const float *wh1, *wh2, *b_in, *pos, *bv_sa, *bo_sa, *bv_ca, *bo_ca;
    u16 *xbf, *w_inT, *wff1t, *wff2t, *woT2, *wv2b, *Wh1t, *Wh2t;
    float *bias_in, *b_comb;
};

__device__ __forceinline__ void dev_cvt8(const float* src, u16* dst, int i)
{
    const float4* q = (const float4*)src + (size_t)i * 2;
    const float4 a = q[0], c = q[1];
    u16x8 v;
    v[0] = f2bf(a.x); v[1] = f2bf(a.y); v[2] = f2bf(a.z); v[3] = f2bf(a.w);
    v[4] = f2bf(c.x); v[5] = f2bf(c.y); v[6] = f2bf(c.z); v[7] = f2bf(c.w);
    *(u16x8*)(dst + (size_t)i * 8) = v;
}

__device__ __forceinline__ void dev_transpose(
    const float* in, u16* out, int K, int N, int t, int tid, u16 (*tile)[33])
{
    const int nt = N >> 5;
    const int n0 = (t % nt) * 32, k0 = (t / nt) * 32;
    const int tx = tid & 31, ty = tid >> 5;
#pragma unroll
    for (int i = 0; i < 32; i += 8)
        tile[ty + i][tx] = f2bf(in[(size_t)(k0 + ty + i) * N + (n0 + tx)]);
    __syncthreads();
#pragma unroll
    for (int i = 0; i < 32; i += 8)
        out[(size_t)(n0 + ty + i) * K + (k0 + tx)] = tile[tx][ty + i];
}

__global__ __launch_bounds__(256) void prep_all(PrepPtrs p)
{
    __shared__ u16 tile[32][33];
    __shared__ float psa[4][64], pca[4][64];
    const int tid = threadIdx.x;
    int b = blockIdx.x;
    if (b < 16384) { dev_cvt8(p.x, p.xbf, b * 256 + tid); return; }
    b -= 16384;
    if (b < 2048) { dev_transpose(p.w_in, p.w_inT, 4096, 512, b, tid, tile); return; }
    b -= 2048;
    if (b < 1024) { dev_transpose(p.w_ff1, p.wff1t, 512, 2048, b, tid, tile); return; }
    b -= 1024;
    if (b < 1024) { dev_transpose(p.w_ff2, p.wff2t, 2048, 512, b, tid, tile); return; }
    b -= 1024;
    if (b < 256) { dev_transpose(p.wo_ca, p.woT2, 512, 512, b, tid, tile); return; }
    b -= 256;
    if (b < 256) { dev_transpose(p.wo_sa, p.woT2 + 512 * 512, 512, 512, b, tid, tile); return; }
    b -= 256;
    if (b < 1536) {  // Wh1t[h*256+k][d] = wh1[h][d][k]
        const int idx = b * 256 + tid;
        const int d = idx & 511, j = idx >> 9;
        const int h = j >> 8, kk = j & 255;
        p.Wh1t[idx] = f2bf(p.wh1[((size_t)(h * 512 + d)) * 256 + kk]);
        return;
    }
    b -= 1536;
    if (b < 2688) {  // Wh2t[h][o][k] = wh2[h][k][o]
        const int idx = b * 256 + tid;
        const int kk = idx & 255, t = idx >> 8;
        const int h = t / 896, o = t - h * 896;
        p.Wh2t[idx] = f2bf(p.wh2[((size_t)(h * 256 + kk)) * 896 + o]);
        return;
    }
    b -= 2688;
    if (b < 256) {
        if (b < 128) dev_cvt8(p.wv_ca, p.wv2b, b * 256 + tid);
        else         dev_cvt8(p.wv_sa, p.wv2b + 512 * 512, (b - 128) * 256 + tid);
        return;
    }
    b -= 256;
    {   // bias prep: 8 blocks, block b covers i in [b*64, b*64+64)
        const int ii = tid & 63, kg = tid >> 6;
        const int i = b * 64 + ii;
        float sa = 0.f, ca = 0.f;
        for (int k = kg; k < 512; k += 4) {
            sa += p.bv_sa[k] * p.wo_sa[(size_t)k * 512 + i];
            ca += p.bv_ca[k] * p.wo_ca[(size_t)k * 512 + i];
        }
        psa[kg][ii] = sa; pca[kg][ii] = ca;
        __syncthreads();
        if (kg == 0) {
            p.bias_in[i] = p.b_in[i] + p.pos[i];
            p.b_comb[i] = psa[0][ii] + psa[1][ii] + psa[2][ii] + psa[3][ii]
                        + pca[0][ii] + pca[1][ii] + pca[2][ii] + pca[3][ii]
                        + p.bo_sa[i] + p.bo_ca[i];
        }
    }
}

extern "C" void kernel_launch(void* const* d_in, const int* in_sizes, int n_in,
                              void* d_out, int out_size, void* d_ws, size_t ws_size,
                              hipStream_t stream)
{
    const float* ln1_g  = (const float*)d_in[4];
    const float* ln1_b  = (const float*)d_in[5];
    const float* ln3_g  = (const float*)d_in[16];
    const float* ln3_b  = (const float*)d_in[17];
    const float* b_ff1  = (const float*)d_in[19];
    const float* b_ff2  = (const float*)d_in[21];
    const float* lnoutg = (const float*)d_in[22];
    const float* lnoutb = (const float*)d_in[23];
    const float* bh1    = (const float*)d_in[25];
    const float* lnh_g  = (const float*)d_in[26];
    const float* lnh_b  = (const float*)d_in[27];
    const float* bh2    = (const float*)d_in[29];
    float* out = (float*)d_out;
    const int KBIG = 0x7fffffff;

    // ---- workspace layout (~70 MB, rewritten fully every call) ----
    char* wsp = (char*)d_ws;
    size_t off = 0;
    auto ALLOC = [&](size_t n) { char* r = wsp + off; off = (off + n + 255) & ~(size_t)255; return r; };
    u16* w_inT  = (u16*)ALLOC(512UL * 4096 * 2);
    u16* wff1t  = (u16*)ALLOC(2048UL * 512 * 2);
    u16* wff2t  = (u16*)ALLOC(512UL * 2048 * 2);
    u16* woT2   = (u16*)ALLOC(2UL * 512 * 512 * 2);
    u16* wv2b   = (u16*)ALLOC(2UL * 512 * 512 * 2);
    u16* Wct    = (u16*)ALLOC(512UL * 1024 * 2);
    u16* Wh1t   = (u16*)ALLOC(768UL * 512 * 2);
    u16* Wh2t   = (u16*)ALLOC(3UL * 896 * 256 * 2);
    float* bias_in = (float*)ALLOC(512 * 4);
    float* b_comb  = (float*)ALLOC(512 * 4);
    u16* h0   = (u16*)ALLOC(8192UL * 512 * 2);
    u16* T    = (u16*)ALLOC(8192UL * 512 * 2);
    u16* hbuf = (u16*)ALLOC(8192UL * 512 * 2);
    u16* G    = (u16*)ALLOC(8192UL * 2048 * 2);  // FF inter; partials; Z/Z2
    u16* Z  = G;
    u16* Z2 = (u16*)((char*)G + 8192UL * 768 * 2);
    // d_out (88 MB) lifetime: xbf [prep -> GEMM1], FF2 partials, final output
    u16*   xbf   = (u16*)d_out;                  // 8192x4096 bf16 = 67 MB
    float* partG = (float*)G;                    // GEMM1/attn partials x2
    float* partO = out;                          // FF2 partials x2
    const long PZS = 8192L * 512;

    // ---- consolidated prep (1 launch, includes x -> bf16) ----
    PrepPtrs pp;
    pp.x = (const float*)d_in[0];
    pp.w_in = (const float*)d_in[1];  pp.w_ff1 = (const float*)d_in[18];
    pp.w_ff2 = (const float*)d_in[20];
    pp.wo_ca = (const float*)d_in[14]; pp.wo_sa = (const float*)d_in[8];
    pp.wv_ca = (const float*)d_in[12]; pp.wv_sa = (const float*)d_in[6];
    pp.wh1 = (const float*)d_in[24];   pp.wh2 = (const float*)d_in[28];
    pp.b_in = (const float*)d_in[2];   pp.pos = (const float*)d_in[3];
    pp.bv_sa = (const float*)d_in[7];  pp.bo_sa = (const float*)d_in[9];
    pp.bv_ca = (const float*)d_in[13]; pp.bo_ca = (const float*)d_in[15];
    pp.xbf = xbf;
    pp.w_inT = w_inT; pp.wff1t = wff1t; pp.wff2t = wff2t;
    pp.woT2 = woT2; pp.wv2b = wv2b; pp.Wh1t = Wh1t; pp.Wh2t = Wh2t;
    pp.bias_in = bias_in; pp.b_comb = b_comb;
    prep_all<<<25480, 256, 0, stream>>>(pp);
    // Wct (z-batched): z=0 -> ca half (k<512), z=1 -> sa half (k>=512)
    gemm64<false, false, false, false><<<dim3(8, 4, 2), 256, 0, stream>>>(
        woT2, nullptr, KBIG, wv2b, nullptr, nullptr, 0, Wct,
        512, 512, 512, 1024, 512 * 512, 512 * 512, 0, 512, 0);

    // ---- main pipeline ----
    // GEMM1 (bf16 A = xbf) split-K x2 -> partials in G; fused reduce -> h0, T=ln1
    gemm64<false, false, false, true><<<dim3(128, 4, 2), 256, 0, stream>>>(
        xbf, nullptr, KBIG, w_inT, nullptr, nullptr, 0, partG,
        4096, 4096, 4096, 512, 0, 0, 0, PZS, 2048);
    reduceLN512<2, false, true><<<2048, 256, 0, stream>>>(
        partG, PZS, bias_in, nullptr, ln1_g, ln1_b, h0, T);
    // attention split-K x2: [h0 | T] @ Wct -> partials in G; fused reduce
    // +b_comb +h0 residual -> hbuf=h2, T=ln3
    gemm64<false, false, false, true><<<dim3(128, 4, 2), 256, 0, stream>>>(
        h0, T, 512, Wct, nullptr, nullptr, 0, partG,
        1024, 512, 1024, 512, 0, 0, 0, PZS, 512);
    reduceLN512<2, true, true><<<2048, 256, 0, stream>>>(
        partG, PZS, b_comb, h0, ln3_g, ln3_b, hbuf, T);
    // G = gelu(T @ w_ff1 + b_ff1)   [8192, 2048]
    gemm64<true, false, false, false><<<dim3(128, 16), 256, 0, stream>>>(
        T, nullptr, KBIG, wff1t, b_ff1, nullptr, 0, G,
        512, 512, 512, 2048, 0, 0, 0, 0, 0);
    // FF2 split-K x2 -> partials in d_out (xbf dead); fused reduce +b_ff2
    // +h2 residual -> T=lnout
    gemm64<false, false, false, true><<<dim3(128, 4, 2), 256, 0, stream>>>(
        G, nullptr, KBIG, wff2t, nullptr, nullptr, 0, partO,
        2048, 2048, 2048, 512, 0, 0, 0, PZS, 1024);
    reduceLN512<2, true, false><<<2048, 256, 0, stream>>>(
        partO, PZS, b_ff2, hbuf, lnoutg, lnoutb, nullptr, T);
    // Z = gelu(T @ Wh1 + bh1)   [8192, 768]
    gemm64<true, false, false, false><<<dim3(128, 6), 256, 0, stream>>>(
        T, nullptr, KBIG, Wh1t, bh1, nullptr, 0, Z,
        512, 512, 512, 768, 0, 0, 0, 0, 0);
    // Z2 = per-head LN(Z)
    lnh_kernel<<<6144, 256, 0, stream>>>(Z, lnh_g, lnh_b, Z2);
    // out[:, z*896:(z+1)*896] = Z2[:, z*256:+256] @ wh2[z] + bh2[z]
    // (f32, z-batched; overwrites ALL of d_out)
    gemm64<false, false, true, false><<<dim3(128, 7, 3), 256, 0, stream>>>(
        Z2, nullptr, KBIG, Wh2t, bh2, nullptr, 0, out,
        256, 768, 256, 2688, 256, 896 * 256, 896, 896, 0);
}

// Round 20
// 297.165 us; speedup vs baseline: 1.4314x; 1.1221x over previous
//
#include <hip/hip_runtime.h>
#include <math.h>

// ---------------------------------------------------------------------------
// RFSQDraftModelWithProjection — f32 in / f32 out, bf16 MFMA compute.
// r20: prep_all restructured: bias-prep FIRST (latency hides under streaming
// blocks, x4 unroll), Wh1t/Wh2t gathers converted to per-head LDS-tile
// transposes (coalesced both sides). Pipeline unchanged from r19:
// BK=64 gemm64 (0 bank conflicts), xbf in d_out, split-K partials in G/d_out,
// fused reduceLN, fast GELU.
// ---------------------------------------------------------------------------

typedef unsigned short u16;
typedef __attribute__((ext_vector_type(8))) short bf16x8;
typedef __attribute__((ext_vector_type(4))) float f32x4;
typedef __attribute__((ext_vector_type(8))) unsigned short u16x8;
typedef __attribute__((ext_vector_type(4))) unsigned short u16x4;

__device__ __forceinline__ float bf2f(u16 u){
    union { unsigned int i; float f; } x; x.i = ((unsigned int)u) << 16; return x.f;
}
__device__ __forceinline__ u16 f2bf(float f){
    union { float f; unsigned int i; } x; x.f = f;
    unsigned int r = x.i + 0x7fffu + ((x.i >> 16) & 1u);
    return (u16)(r >> 16);
}
__device__ __forceinline__ float gelu_fast(float v){
    const float u = 1.5957691216f * v * (1.0f + 0.044715f * v * v);
    const float e = __expf(u);
    return v * (1.0f - 1.0f / (e + 1.0f));
}
#define GLOAD16(src, dst) __builtin_amdgcn_global_load_lds( \
    (const __attribute__((address_space(1))) void*)(src),   \
    (__attribute__((address_space(3))) void*)(dst), 16, 0, 0)
#define SCHED0 __builtin_amdgcn_sched_barrier(0)

// ---------------------------------------------------------------------------
// gemm64: C[M,N] = A[M,K] @ B[K,N] (+bias +res, opt GELU). 64x128 tile,
// BK=64, 4 waves, 16 MFMA/step, counted-vmcnt double buffer.
// LDS (row, c) holds global chunk (row, c ^ (row&7)); ds_read XORs the same.
// blockIdx.x = m-tile (XCD A-panel reuse), blockIdx.y = n-tile.
// A2/ksplit: concat A at k=ksplit (64 | ksplit).  PART: z = k-chunk
// (kch%64==0), f32 partials at Cout+z*czs.  Else z = batch via strides.
// ---------------------------------------------------------------------------
template<bool GELU, bool RES, bool OUTF32, bool PART>
__global__ __launch_bounds__(256) void gemm64(
    const u16* __restrict__ A, const u16* __restrict__ A2, int ksplit,
    const u16* __restrict__ Bt, const float* __restrict__ bias,
    const u16* __restrict__ res, int ldr,
    void* __restrict__ Cout, int K, int lda, int ldb, int ldc,
    long azs, long bzs, int biaszs, long czs, int kch)
{
    __shared__ __align__(16) u16 As[2][64 * 64];
    __shared__ __align__(16) u16 Bs[2][128 * 64];
    const int tid = threadIdx.x;
    const int w = tid >> 6, l = tid & 63;
    const int wr = w >> 1, wc = w & 1;
    const int m0 = blockIdx.x * 64, n0 = blockIdx.y * 128;
    const int z = blockIdx.z;
    int kbeg = 0, kend = K;
    if (PART) { kbeg = z * kch; kend = min(kbeg + kch, K); }
    const u16* A16 = A + (PART ? 0 : (size_t)z * azs);
    const u16* BtZ = Bt + (PART ? 0 : (size_t)z * bzs);
    const int swc = (l & 7) ^ (l >> 3);   // pre-swizzled source chunk

    f32x4 acc[2][4];
#pragma unroll
    for (int i = 0; i < 2; ++i)
#pragma unroll
        for (int j = 0; j < 4; ++j) acc[i][j] = (f32x4){0.f, 0.f, 0.f, 0.f};

    auto stageB = [&](int buf, int k0) {
#pragma unroll
        for (int j = 0; j < 4; ++j) {
            const int rb = w * 32 + j * 8;
            const u16* gb = BtZ + (size_t)(n0 + rb + (l >> 3)) * ldb + k0 + swc * 8;
            GLOAD16(gb, &Bs[buf][rb * 64]);
        }
    };
    auto stageA16 = [&](int buf, int k0) {
        const u16* base = (k0 >= ksplit) ? (A2 + (k0 - ksplit)) : (A16 + k0);
#pragma unroll
        for (int j = 0; j < 2; ++j) {
            const int rb = w * 16 + j * 8;
            const u16* ga = base + (size_t)(m0 + rb + (l >> 3)) * lda + swc * 8;
            GLOAD16(ga, &As[buf][rb * 64]);
        }
    };
    int cur = 0;
    auto compute = [&]() {
#pragma unroll
        for (int kk = 0; kk < 2; ++kk) {
            const int kcb = kk * 4 + (l >> 4);
            bf16x8 a[2], b[4];
#pragma unroll
            for (int i = 0; i < 2; ++i) {
                const int row = wr * 32 + i * 16 + (l & 15);
                a[i] = *(const bf16x8*)&As[cur][row * 64 + (kcb ^ (l & 7)) * 8];
            }
#pragma unroll
            for (int j = 0; j < 4; ++j) {
                const int row = wc * 64 + j * 16 + (l & 15);
                b[j] = *(const bf16x8*)&Bs[cur][row * 64 + (kcb ^ (l & 7)) * 8];
            }
#pragma unroll
            for (int i = 0; i < 2; ++i)
#pragma unroll
                for (int j = 0; j < 4; ++j)
                    acc[i][j] = __builtin_amdgcn_mfma_f32_16x16x32_bf16(a[i], b[j], acc[i][j], 0, 0, 0);
        }
    };

    const int nt = (kend - kbeg) >> 6;
    stageA16(0, kbeg);
    stageB(0, kbeg);
    for (int t = 0; t < nt; ++t) {
        const bool more = (t + 1) < nt;
        if (more) {
            const int kn = kbeg + ((t + 1) << 6);
            stageA16(cur ^ 1, kn);
            stageB(cur ^ 1, kn);
        }
        if (more) asm volatile("s_waitcnt vmcnt(6)" ::: "memory");
        else      asm volatile("s_waitcnt vmcnt(0)" ::: "memory");
        SCHED0;
        __builtin_amdgcn_s_barrier();
        SCHED0;
        compute();
        asm volatile("" ::: "memory");
        SCHED0;
        __builtin_amdgcn_s_barrier();
        SCHED0;
        cur ^= 1;
    }

    // epilogue: C/D layout col = l&15, row = (l>>4)*4 + r  [m89/m91]
    float* cF = (float*)Cout + (size_t)z * czs;
    u16*   cH = (u16*)Cout + (size_t)z * czs;
    const float* biasZ = (!PART && bias) ? bias + (size_t)z * biaszs : nullptr;
#pragma unroll
    for (int i = 0; i < 2; ++i) {
#pragma unroll
        for (int j = 0; j < 4; ++j) {
            const int col = n0 + wc * 64 + j * 16 + (l & 15);
            const int rowb = m0 + wr * 32 + i * 16 + (l >> 4) * 4;
#pragma unroll
            for (int r = 0; r < 4; ++r) {
                const int row = rowb + r;
                float v = acc[i][j][r];
                if (PART) {
                    cF[(size_t)row * ldc + col] = v;
                } else {
                    if (biasZ) v += biasZ[col];
                    if (RES) v += bf2f(res[(size_t)row * ldr + col]);
                    if (GELU) v = gelu_fast(v);
                    if (OUTF32) cF[(size_t)row * ldc + col] = v;
                    else        cH[(size_t)row * ldc + col] = f2bf(v);
                }
            }
        }
    }
}

// ---------------------------------------------------------------------------
// reduceLN512: fused split-K reduce + bias (+res) -> optional bf16 H-write,
// then row LayerNorm (512 cols) -> bf16 T-write. One wave per row.
// ---------------------------------------------------------------------------
template<int NP, bool RES, bool WRITEH>
__global__ __launch_bounds__(256) void reduceLN512(
    const float* __restrict__ part, long pzs, const float* __restrict__ bias,
    const u16* __restrict__ res, const float* __restrict__ g,
    const float* __restrict__ b, u16* __restrict__ outH, u16* __restrict__ outT)
{
    const int wid = threadIdx.x >> 6, l = threadIdx.x & 63;
    const size_t row = (size_t)blockIdx.x * 4 + wid;
    const size_t base = row * 512 + l * 8;
    float f[8];
    {
        const float4 p0 = *(const float4*)(part + base);
        const float4 p1 = *(const float4*)(part + base + 4);
        f[0]=p0.x; f[1]=p0.y; f[2]=p0.z; f[3]=p0.w;
        f[4]=p1.x; f[5]=p1.y; f[6]=p1.z; f[7]=p1.w;
    }
#pragma unroll
    for (int p = 1; p < NP; ++p) {
        const float4 p0 = *(const float4*)(part + (size_t)p * pzs + base);
        const float4 p1 = *(const float4*)(part + (size_t)p * pzs + base + 4);
        f[0]+=p0.x; f[1]+=p0.y; f[2]+=p0.z; f[3]+=p0.w;
        f[4]+=p1.x; f[5]+=p1.y; f[6]+=p1.z; f[7]+=p1.w;
    }
    {
        const float4 b0 = *(const float4*)(bias + l * 8);
        const float4 b1 = *(const float4*)(bias + l * 8 + 4);
        f[0]+=b0.x; f[1]+=b0.y; f[2]+=b0.z; f[3]+=b0.w;
        f[4]+=b1.x; f[5]+=b1.y; f[6]+=b1.z; f[7]+=b1.w;
    }
    if (RES) {
        const u16x8 r = *(const u16x8*)(res + base);
#pragma unroll
        for (int j = 0; j < 8; ++j) f[j] += bf2f(r[j]);
    }
    if (WRITEH) {
        u16x8 h;
#pragma unroll
        for (int j = 0; j < 8; ++j) h[j] = f2bf(f[j]);
        *(u16x8*)(outH + base) = h;
    }
    float s = 0.f, q = 0.f;
#pragma unroll
    for (int j = 0; j < 8; ++j) { s += f[j]; q += f[j] * f[j]; }
#pragma unroll
    for (int o = 32; o > 0; o >>= 1) { s += __shfl_xor(s, o); q += __shfl_xor(q, o); }
    const float mean = s * (1.f / 512.f);
    const float var = q * (1.f / 512.f) - mean * mean;
    const float rstd = rsqrtf(var + 1e-5f);
    u16x8 t;
#pragma unroll
    for (int j = 0; j < 8; ++j) {
        const int c = l * 8 + j;
        t[j] = f2bf((f[j] - mean) * rstd * g[c] + b[c]);
    }
    *(u16x8*)(outT + base) = t;
}

// per-head LN over 256 (rows are [8192,768], heads of 256), wave per (row,head)
__global__ __launch_bounds__(256) void lnh_kernel(
    const u16* __restrict__ in, const float* __restrict__ g,
    const float* __restrict__ b, u16* __restrict__ out)
{
    const int wid = threadIdx.x >> 6, l = threadIdx.x & 63;
    const int unit = blockIdx.x * 4 + wid;        // unit = h*8192 + row
    const int h = unit >> 13, row = unit & 8191;
    const size_t base = (size_t)row * 768 + h * 256 + l * 4;
    u16x4 v = *(const u16x4*)(in + base);
    float f[4], s = 0.f, q = 0.f;
#pragma unroll
    for (int j = 0; j < 4; ++j) { f[j] = bf2f(v[j]); s += f[j]; q += f[j] * f[j]; }
#pragma unroll
    for (int o = 32; o > 0; o >>= 1) { s += __shfl_xor(s, o); q += __shfl_xor(q, o); }
    const float mean = s * (1.f / 256.f);
    const float var = q * (1.f / 256.f) - mean * mean;
    const float rstd = rsqrtf(var + 1e-5f);
    u16x4 ov;
#pragma unroll
    for (int j = 0; j < 4; ++j) {
        const int c = h * 256 + l * 4 + j;
        ov[j] = f2bf((f[j] - mean) * rstd * g[c] + b[c]);
    }
    *(u16x4*)(out + base) = ov;
}

// ---------------------------------------------------------------------------
// prep_all (22312 blocks): bias-prep FIRST so its latency-serial loop hides
// under the streaming segments; Wh1t/Wh2t as per-head LDS-tile transposes.
// [0,8) bias | [,136) cvt wv_ca | [,264) cvt wv_sa | [,16648) cvt x
// | [,18696) w_inT | [,19720) wff1t | [,20744) wff2t | [,21000) woTca
// | [,21256) woTsa | [,21640) Wh1t (3x128 tiles) | [,22312) Wh2t (3x224).
// ---------------------------------------------------------------------------
struct PrepPtrs {
    const float *x, *w_in, *w_ff1, *w_ff2, *wo_ca, *wo_sa, *wv_ca, *wv_sa;
    const float *wh1, *wh2, *b_in, *pos, *bv_sa, *bo_sa, *bv_ca, *bo_ca;
    u16 *xbf, *w_inT, *wff1t, *wff2t, *woT2, *wv2b, *Wh1t, *Wh2t;
    float *bias_in, *b_comb;
};

__device__ __forceinline__ void dev_cvt8(const float* src, u16* dst, int i)
{
    const float4* q = (const float4*)src + (size_t)i * 2;
    const float4 a = q[0], c = q[1];
    u16x8 v;
    v[0] = f2bf(a.x); v[1] = f2bf(a.y); v[2] = f2bf(a.z); v[3] = f2bf(a.w);
    v[4] = f2bf(c.x); v[5] = f2bf(c.y); v[6] = f2bf(c.z); v[7] = f2bf(c.w);
    *(u16x8*)(dst + (size_t)i * 8) = v;
}

__device__ __forceinline__ void dev_transpose(
    const float* in, u16* out, int K, int N, int t, int tid, u16 (*tile)[33])
{
    const int nt = N >> 5;
    const int n0 = (t % nt) * 32, k0 = (t / nt) * 32;
    const int tx = tid & 31, ty = tid >> 5;
#pragma unroll
    for (int i = 0; i < 32; i += 8)
        tile[ty + i][tx] = f2bf(in[(size_t)(k0 + ty + i) * N + (n0 + tx)]);
    __syncthreads();
#pragma unroll
    for (int i = 0; i < 32; i += 8)
        out[(size_t)(n0 + ty + i) * K + (k0 + tx)] = tile[tx][ty + i];
}

__global__ __launch_bounds__(256) void prep_all(PrepPtrs p)
{
    __shared__ u16 tile[32][33];
    __shared__ float psa[4][64], pca[4][64];
    const int tid = threadIdx.x;
    int b = blockIdx.x;
    if (b < 8) {   // bias prep (runs first; overlaps all streaming blocks)
        const int ii = tid & 63, kg = tid >> 6;
        const int i = b * 64 + ii;
        float sa = 0.f, ca = 0.f;
#pragma unroll 4
        for (int k = kg; k < 512; k += 4) {
            sa += p.bv_sa[k] * p.wo_sa[(size_t)k * 512 + i];
            ca += p.bv_ca[k] * p.wo_ca[(size_t)k * 512 + i];
        }
        psa[kg][ii] = sa; pca[kg][ii] = ca;
        __syncthreads();
        if (kg == 0) {
            p.bias_in[i] = p.b_in[i] + p.pos[i];
            p.b_comb[i] = psa[0][ii] + psa[1][ii] + psa[2][ii] + psa[3][ii]
                        + pca[0][ii] + pca[1][ii] + pca[2][ii] + pca[3][ii]
                        + p.bo_sa[i] + p.bo_ca[i];
        }
        return;
    }
    b -= 8;
    if (b < 256) {
        if (b < 128) dev_cvt8(p.wv_ca, p.wv2b, b * 256 + tid);
        else         dev_cvt8(p.wv_sa, p.wv2b + 512 * 512, (b - 128) * 256 + tid);
        return;
    }
    b -= 256;
    if (b < 16384) { dev_cvt8(p.x, p.xbf, b * 256 + tid); return; }
    b -= 16384;
    if (b < 2048) { dev_transpose(p.w_in, p.w_inT, 4096, 512, b, tid, tile); return; }
    b -= 2048;
    if (b < 1024) { dev_transpose(p.w_ff1, p.wff1t, 512, 2048, b, tid, tile); return; }
    b -= 1024;
    if (b < 1024) { dev_transpose(p.w_ff2, p.wff2t, 2048, 512, b, tid, tile); return; }
    b -= 1024;
    if (b < 256) { dev_transpose(p.wo_ca, p.woT2, 512, 512, b, tid, tile); return; }
    b -= 256;
    if (b < 256) { dev_transpose(p.wo_sa, p.woT2 + 512 * 512, 512, 512, b, tid, tile); return; }
    b -= 256;
    if (b < 384) {  // Wh1t: per-head transpose [512 d][256 k] -> [256 k][512 d]
        const int h = b / 128, t = b % 128;
        dev_transpose(p.wh1 + (size_t)h * 512 * 256,
                      p.Wh1t + (size_t)h * 256 * 512, 512, 256, t, tid, tile);
        return;
    }
    b -= 384;
    {   // Wh2t: per-head transpose [256 k][896 o] -> [896 o][256 k]
        const int h = b / 224, t = b % 224;
        dev_transpose(p.wh2 + (size_t)h * 256 * 896,
                      p.Wh2t + (size_t)h * 896 * 256, 256, 896, t, tid, tile);
    }
}

extern "C" void kernel_launch(void* const* d_in, const int* in_sizes, int n_in,
                              void* d_out, int out_size, void* d_ws, size_t ws_size,
                              hipStream_t stream)
{
    const float* ln1_g  = (const float*)d_in[4];
    const float* ln1_b  = (const float*)d_in[5];
    const float* ln3_g  = (const float*)d_in[16];
    const float* ln3_b  = (const float*)d_in[17];
    const float* b_ff1  = (const float*)d_in[19];
    const float* b_ff2  = (const float*)d_in[21];
    const float* lnoutg = (const float*)d_in[22];
    const float* lnoutb = (const float*)d_in[23];
    const float* bh1    = (const float*)d_in[25];
    const float* lnh_g  = (const float*)d_in[26];
    const float* lnh_b  = (const float*)d_in[27];
    const float* bh2    = (const float*)d_in[29];
    float* out = (float*)d_out;
    const int KBIG = 0x7fffffff;

    // ---- workspace layout (~70 MB, rewritten fully every call) ----
    char* wsp = (char*)d_ws;
    size_t off = 0;
    auto ALLOC = [&](size_t n) { char* r = wsp + off; off = (off + n + 255) & ~(size_t)255; return r; };
    u16* w_inT  = (u16*)ALLOC(512UL * 4096 * 2);
    u16* wff1t  = (u16*)ALLOC(2048UL * 512 * 2);
    u16* wff2t  = (u16*)ALLOC(512UL * 2048 * 2);
    u16* woT2   = (u16*)ALLOC(2UL * 512 * 512 * 2);
    u16* wv2b   = (u16*)ALLOC(2UL * 512 * 512 * 2);
    u16* Wct    = (u16*)ALLOC(512UL * 1024 * 2);
    u16* Wh1t   = (u16*)ALLOC(768UL * 512 * 2);
    u16* Wh2t   = (u16*)ALLOC(3UL * 896 * 256 * 2);
    float* bias_in = (float*)ALLOC(512 * 4);
    float* b_comb  = (float*)ALLOC(512 * 4);
    u16* h0   = (u16*)ALLOC(8192UL * 512 * 2);
    u16* T    = (u16*)ALLOC(8192UL * 512 * 2);
    u16* hbuf = (u16*)ALLOC(8192UL * 512 * 2);
    u16* G    = (u16*)ALLOC(8192UL * 2048 * 2);  // FF inter; partials; Z/Z2
    u16* Z  = G;
    u16* Z2 = (u16*)((char*)G + 8192UL * 768 * 2);
    // d_out (88 MB) lifetime: xbf [prep -> GEMM1], FF2 partials, final output
    u16*   xbf   = (u16*)d_out;                  // 8192x4096 bf16 = 67 MB
    float* partG = (float*)G;                    // GEMM1/attn partials x2
    float* partO = out;                          // FF2 partials x2
    const long PZS = 8192L * 512;

    // ---- consolidated prep (1 launch, includes x -> bf16) ----
    PrepPtrs pp;
    pp.x = (const float*)d_in[0];
    pp.w_in = (const float*)d_in[1];  pp.w_ff1 = (const float*)d_in[18];
    pp.w_ff2 = (const float*)d_in[20];
    pp.wo_ca = (const float*)d_in[14]; pp.wo_sa = (const float*)d_in[8];
    pp.wv_ca = (const float*)d_in[12]; pp.wv_sa = (const float*)d_in[6];
    pp.wh1 = (const float*)d_in[24];   pp.wh2 = (const float*)d_in[28];
    pp.b_in = (const float*)d_in[2];   pp.pos = (const float*)d_in[3];
    pp.bv_sa = (const float*)d_in[7];  pp.bo_sa = (const float*)d_in[9];
    pp.bv_ca = (const float*)d_in[13]; pp.bo_ca = (const float*)d_in[15];
    pp.xbf = xbf;
    pp.w_inT = w_inT; pp.wff1t = wff1t; pp.wff2t = wff2t;
    pp.woT2 = woT2; pp.wv2b = wv2b; pp.Wh1t = Wh1t; pp.Wh2t = Wh2t;
    pp.bias_in = bias_in; pp.b_comb = b_comb;
    prep_all<<<22312, 256, 0, stream>>>(pp);
    // Wct (z-batched): z=0 -> ca half (k<512), z=1 -> sa half (k>=512)
    gemm64<false, false, false, false><<<dim3(8, 4, 2), 256, 0, stream>>>(
        woT2, nullptr, KBIG, wv2b, nullptr, nullptr, 0, Wct,
        512, 512, 512, 1024, 512 * 512, 512 * 512, 0, 512, 0);

    // ---- main pipeline ----
    // GEMM1 (bf16 A = xbf) split-K x2 -> partials in G; fused reduce -> h0, T=ln1
    gemm64<false, false, false, true><<<dim3(128, 4, 2), 256, 0, stream>>>(
        xbf, nullptr, KBIG, w_inT, nullptr, nullptr, 0, partG,
        4096, 4096, 4096, 512, 0, 0, 0, PZS, 2048);
    reduceLN512<2, false, true><<<2048, 256, 0, stream>>>(
        partG, PZS, bias_in, nullptr, ln1_g, ln1_b, h0, T);
    // attention split-K x2: [h0 | T] @ Wct -> partials in G; fused reduce
    // +b_comb +h0 residual -> hbuf=h2, T=ln3
    gemm64<false, false, false, true><<<dim3(128, 4, 2), 256, 0, stream>>>(
        h0, T, 512, Wct, nullptr, nullptr, 0, partG,
        1024, 512, 1024, 512, 0, 0, 0, PZS, 512);
    reduceLN512<2, true, true><<<2048, 256, 0, stream>>>(
        partG, PZS, b_comb, h0, ln3_g, ln3_b, hbuf, T);
    // G = gelu(T @ w_ff1 + b_ff1)   [8192, 2048]
    gemm64<true, false, false, false><<<dim3(128, 16), 256, 0, stream>>>(
        T, nullptr, KBIG, wff1t, b_ff1, nullptr, 0, G,
        512, 512, 512, 2048, 0, 0, 0, 0, 0);
    // FF2 split-K x2 -> partials in d_out (xbf dead); fused reduce +b_ff2
    // +h2 residual -> T=lnout
    gemm64<false, false, false, true><<<dim3(128, 4, 2), 256, 0, stream>>>(
        G, nullptr, KBIG, wff2t, nullptr, nullptr, 0, partO,
        2048, 2048, 2048, 512, 0, 0, 0, PZS, 1024);
    reduceLN512<2, true, false><<<2048, 256, 0, stream>>>(
        partO, PZS, b_ff2, hbuf, lnoutg, lnoutb, nullptr, T);
    // Z = gelu(T @ Wh1 + bh1)   [8192, 768]
    gemm64<true, false, false, false><<<dim3(128, 6), 256, 0, stream>>>(
        T, nullptr, KBIG, Wh1t, bh1, nullptr, 0, Z,
        512, 512, 512, 768, 0, 0, 0, 0, 0);
    // Z2 = per-head LN(Z)
    lnh_kernel<<<6144, 256, 0, stream>>>(Z, lnh_g, lnh_b, Z2);
    // out[:, z*896:(z+1)*896] = Z2[:, z*256:+256] @ wh2[z] + bh2[z]
    // (f32, z-batched; overwrites ALL of d_out)
    gemm64<false, false, true, false><<<dim3(128, 7, 3), 256, 0, stream>>>(
        Z2, nullptr, KBIG, Wh2t, bh2, nullptr, 0, out,
        256, 768, 256, 2688, 256, 896 * 256, 896, 896, 0);
}